// Round 7
// baseline (431.095 us; speedup 1.0000x reference)
//
#include <hip/hip_runtime.h>

// HetGNN fused kernel, round 21: transposed orientation + lane-private LDS
// backing for the long-lived packed arrays.
// R19/R20: structure right (bank conflicts 0, activation transposes gone),
// but the register-resident design needs ~200 unified regs vs the hard 128
// cap (7 rounds of evidence) -> allocator spilled the long-lived arrays
// (aPf/ePp/m1p) to scratch: 1.3 GB HBM traffic, 320 us. Fix: those arrays
// are lane-private u32[8] -- back them with SoA LDS (elem i at i*256B +
// lane*4B, stride-4 = 2 lanes/bank = conflict-free, per-wave private, no
// barriers). Bonuses: ePp-in-LDS replaces all 24 ds_bpermute/it with direct
// neighbor reads (3-lane same-address collision = broadcast = free), and
// m1p-in-LDS replaces the 8 ds_swizzle lane^1 in agg with an l^1 read.
// Register live set drops to ~95 (af/ef 16 + m2p 8 + acc 16 + transients +
// weight lookahead) -> fits 128, no spill. LDS 96+48+4.25 = 148.3 KB,
// 1 block/CU. Expected regime: LDS-read bound (~123 KB weights + ~22 KB
// activations per it per wave -> ~16 us aggregate-BW floor).

typedef unsigned short u16;
typedef unsigned int   u32;
typedef __attribute__((ext_vector_type(8))) short short8_t;
typedef __attribute__((ext_vector_type(2))) short short2v;
typedef __attribute__((ext_vector_type(4))) float floatx4;

// u16 offsets of each matrix's fragment block inside sW (fi*512 ordering).
// 96 frags: w51(16) w61(16) w71(16) w52(8) w53(8) w62(8) w63(8) w72(8) w73(8).
#define OFF_W51 0
#define OFF_W61 8192
#define OFF_W71 16384
#define OFF_W52 24576
#define OFF_W53 28672
#define OFF_W62 32768
#define OFF_W63 36864
#define OFF_W72 40960
#define OFF_W73 45056
#define WS_U16  49152

// f32 offsets inside the sConst LDS table.
// CB*: biases in NATURAL f_out order (read as float4 at 16t+4p).
// CWPO: wpost de-interleaved: [0..63] real, [64..127] imag (natural order).
// CWPA/CBPA/CBPE: 64 floats in pi-slot order (32f + 8p + j).
// CWPE: 2 x 64 in pi-slot order.
#define CB51 0
#define CB52 64
#define CB53 128
#define CB61 192
#define CB62 256
#define CB63 320
#define CB71 384
#define CB72 448
#define CB73 512
#define CWPO 576
#define CBPO 704
#define CWPA 768
#define CBPA 832
#define CWPE 896
#define CBPE 1024
#define CSZ  1088

// per-wave activation LDS: 3 SoA arrays x 8 elems x 64 lanes (u32)
#define AW_U32 1536

struct Params {
  const float *ap, *ef;
  const float *wpa, *bpa, *wpe, *bpe;
  const float *w51, *b51, *w52, *b52, *w53, *b53;
  const float *w61, *b61, *w62, *b62, *w63, *b63;
  const float *w71, *b71, *w72, *b72, *w73, *b73;
  const float *wpost, *bpost;
  float *out;
  int gtot;
};

// Pack two f32 to bf16 pair: round-half-up via +0x8000, then one byte-perm.
// Low half = first arg (= even slot j).
__device__ __forceinline__ u32 pk2(float a, float b) {
  const u32 ua = __float_as_uint(a) + 0x8000u;
  const u32 ub = __float_as_uint(b) + 0x8000u;
  return __builtin_amdgcn_perm(ub, ua, 0x07060302u);  // {ub[31:16], ua[31:16]}
}
__device__ __forceinline__ float blo(u32 v) { return __uint_as_float(v << 16); }
__device__ __forceinline__ float bhi(u32 v) { return __uint_as_float(v & 0xffff0000u); }
// packed int16 max: exact bf16-max in our use because the final max-with-0
// (deferred relu) dominates any mis-ordered negative intermediate.
__device__ __forceinline__ u32 pkmax(u32 a, u32 b) {
  const short2v r = __builtin_elementwise_max(__builtin_bit_cast(short2v, a),
                                              __builtin_bit_cast(short2v, b));
  return __builtin_bit_cast(u32, r);
}
// lane ^= 1 exchange (BitMode swizzle, xor=1), used in the epilogue only.
__device__ __forceinline__ u32 swz1(u32 x) {
  return (u32)__builtin_amdgcn_ds_swizzle((int)x, 0x041F);
}

__device__ __forceinline__ floatx4 mfma16(short8_t a, short8_t b, floatx4 c) {
  return __builtin_amdgcn_mfma_f32_16x16x32_bf16(a, b, c, 0, 0, 0);
}
__device__ __forceinline__ short8_t ldW(const u16* B, int f, int l) {
  return *(const short8_t*)(B + f * 512 + l * 8);
}
__device__ __forceinline__ short8_t mkf(u32 a, u32 b, u32 c, u32 d) {
  uint4 v; v.x = a; v.y = b; v.z = c; v.w = d;
  return __builtin_bit_cast(short8_t, v);
}

__device__ __forceinline__ void init0(floatx4* acc) {
#pragma unroll
  for (int t = 0; t < 4; ++t) { acc[t][0] = 0.f; acc[t][1] = 0.f; acc[t][2] = 0.f; acc[t][3] = 0.f; }
}
// Bias init: acc[t][r] = bias[16t + 4p + r] (f_out-indexed, broadcast b128).
__device__ __forceinline__ void initB(floatx4* acc, const float* cb, int qp) {
#pragma unroll
  for (int t = 0; t < 4; ++t) {
    const float4 b = *(const float4*)(cb + 16 * t + 4 * qp);
    acc[t][0] = b.x; acc[t][1] = b.y; acc[t][2] = b.z; acc[t][3] = b.w;
  }
}

// 64->64 layer, weights from LDS: frags (t*TS+0, t*TS+1).
template<int TS>
__device__ __forceinline__ void layerT(floatx4* acc, const u16* W,
                                       short8_t b0, short8_t b1, int l) {
#pragma unroll
  for (int t = 0; t < 4; ++t) {
    acc[t] = mfma16(ldW(W, t * TS + 0, l), b0, acc[t]);
    acc[t] = mfma16(ldW(W, t * TS + 1, l), b1, acc[t]);
  }
}
// K=128 layer (concat input = 4 B-frags), weights = 16 frags (t*4+h).
__device__ __forceinline__ void layerT128(floatx4* acc, const u16* W,
                                          short8_t f0, short8_t f1,
                                          short8_t f2, short8_t f3, int l) {
#pragma unroll
  for (int t = 0; t < 4; ++t) {
    acc[t] = mfma16(ldW(W, t * 4 + 0, l), f0, acc[t]);
    acc[t] = mfma16(ldW(W, t * 4 + 1, l), f1, acc[t]);
    acc[t] = mfma16(ldW(W, t * 4 + 2, l), f2, acc[t]);
    acc[t] = mfma16(ldW(W, t * 4 + 3, l), f3, acc[t]);
  }
}

// relu + pack acc -> next-layer B-frags (pi order: frag0 = pk01[t], frag1 = pk23[t]).
__device__ __forceinline__ void packRf(short8_t& f0, short8_t& f1, const floatx4* a) {
  uint4 u0, u1;
  u0.x = pk2(fmaxf(a[0][0], 0.f), fmaxf(a[0][1], 0.f));
  u1.x = pk2(fmaxf(a[0][2], 0.f), fmaxf(a[0][3], 0.f));
  u0.y = pk2(fmaxf(a[1][0], 0.f), fmaxf(a[1][1], 0.f));
  u1.y = pk2(fmaxf(a[1][2], 0.f), fmaxf(a[1][3], 0.f));
  u0.z = pk2(fmaxf(a[2][0], 0.f), fmaxf(a[2][1], 0.f));
  u1.z = pk2(fmaxf(a[2][2], 0.f), fmaxf(a[2][3], 0.f));
  u0.w = pk2(fmaxf(a[3][0], 0.f), fmaxf(a[3][1], 0.f));
  u1.w = pk2(fmaxf(a[3][2], 0.f), fmaxf(a[3][3], 0.f));
  f0 = __builtin_bit_cast(short8_t, u0);
  f1 = __builtin_bit_cast(short8_t, u1);
}
// raw pack (relu deferred) straight into SoA LDS: elem i at dst[i*64 + lane].
__device__ __forceinline__ void packL(u32* dst, const floatx4* a, int l) {
#pragma unroll
  for (int t = 0; t < 4; ++t) {
    dst[(2 * t + 0) * 64 + l] = pk2(a[t][0], a[t][1]);
    dst[(2 * t + 1) * 64 + l] = pk2(a[t][2], a[t][3]);
  }
}

#define NBLK 256
#define NWAVE 8
#define PPW  4   // 256 blk * 8 waves * 4 pairs = 8192 pairs = 16384 graphs

__global__ __launch_bounds__(512, 2)
__attribute__((amdgpu_waves_per_eu(2, 2)))
void hetgnn_mfma(Params p) {
  __shared__ __align__(16) u16   sW[WS_U16];            // 96 KB weights
  __shared__ __align__(16) u32   sAct[NWAVE * AW_U32];  // 48 KB: 8 x (aP|eP|m1)
  __shared__ __align__(16) float sConst[CSZ];           // 4.25 KB

  const int tid  = threadIdx.x;
  const int wave = tid >> 6;
  const int l    = tid & 63;
  const int qp   = l >> 4;   // lane quarter
  const int c    = l & 15;   // graph-row column: (g = c>>3, b = (c>>1)&3, k = c&1)

  // ---- stage + swizzle weights: f32 global -> bf16 A-frags in pi-k-order.
  //      A-frag (t,h): value(lane l, j) = W[kidx, 16t + (l&15)]
  //      K=64 mats:  kidx = 16*(j>>1) + 4*(l>>4) + 2*h + (j&1)
  //      K=128 mats: kidx = 64*(h>>1) + 16*(j>>1) + 4*(l>>4) + 2*(h&1) + (j&1)
  {
    for (int fi = wave; fi < 96; fi += NWAVE) {   // wave-uniform fi, 12/wave
      int t, h, mi;
      if (fi < 48) { mi = fi >> 4; const int loc = fi & 15; t = loc >> 2; h = loc & 3; }
      else { const int j2 = fi - 48; mi = 3 + (j2 >> 3); const int loc = j2 & 7; t = loc >> 1; h = loc & 1; }
      const float* W =
          (mi == 0) ? p.w51 : (mi == 1) ? p.w61 : (mi == 2) ? p.w71 :
          (mi == 3) ? p.w52 : (mi == 4) ? p.w53 : (mi == 5) ? p.w62 :
          (mi == 6) ? p.w63 : (mi == 7) ? p.w72 : p.w73;
      const int nn = 16 * t + c;
      float w[8];
#pragma unroll
      for (int jj = 0; jj < 8; ++jj) {
        const int kidx = (fi < 48)
            ? 64 * (h >> 1) + 16 * (jj >> 1) + 4 * qp + 2 * (h & 1) + (jj & 1)
            : 16 * (jj >> 1) + 4 * qp + 2 * h + (jj & 1);
        w[jj] = W[kidx * 64 + nn];
      }
      uint4 o;
      o.x = pk2(w[0], w[1]); o.y = pk2(w[2], w[3]);
      o.z = pk2(w[4], w[5]); o.w = pk2(w[6], w[7]);
      *(uint4*)(sW + fi * 512 + l * 8) = o;
    }
  }
  if (tid < 64) {
    // biases: natural f_out order
    sConst[CB51 + tid] = p.b51[tid];
    sConst[CB52 + tid] = p.b52[tid];
    sConst[CB53 + tid] = p.b53[tid];
    sConst[CB61 + tid] = p.b61[tid];
    sConst[CB62 + tid] = p.b62[tid];
    sConst[CB63 + tid] = p.b63[tid];
    sConst[CB71 + tid] = p.b71[tid];
    sConst[CB72 + tid] = p.b72[tid];
    sConst[CB73 + tid] = p.b73[tid];
    // wpost de-interleaved (natural order)
    sConst[CWPO + tid]      = p.wpost[2 * tid];
    sConst[CWPO + 64 + tid] = p.wpost[2 * tid + 1];
    // pre-layer weights/biases in pi-slot order: slot tid = 32f + 8p + j
    {
      const int f = tid >> 5, pp = (tid >> 3) & 3, jj = tid & 7;
      const int feat = 16 * (jj >> 1) + 4 * pp + 2 * f + (jj & 1);
      sConst[CWPA + tid] = p.wpa[feat];
      sConst[CBPA + tid] = p.bpa[feat];
      sConst[CBPE + tid] = p.bpe[feat];
    }
  }
  if (tid < 128) {
    const int s = tid & 63;
    const int f = s >> 5, pp = (s >> 3) & 3, jj = s & 7;
    const int feat = 16 * (jj >> 1) + 4 * pp + 2 * f + (jj & 1);
    sConst[CWPE + tid] = p.wpe[(tid >> 6) * 64 + feat];
  }
  if (tid < 2) sConst[CBPO + tid] = p.bpost[tid];
  __syncthreads();

  // per-wave SoA activation arrays (lane-private columns, no barriers needed)
  u32* sAP = sAct + wave * AW_U32;        // aP^T packed (b61 folded)
  u32* sEP = sAP + 512;                   // eP^T packed
  u32* sM1 = sAP + 1024;                  // m1 packed (raw, relu deferred)

  // neighbor row index inside the quarter, per j (3-lane collisions broadcast)
  const int b_ln = (c >> 1) & 3;
  int nb[3];
#pragma unroll
  for (int j = 0; j < 3; ++j) {
    const int bp = j + (j >= b_ln);
    nb[j] = (l & 48) + (c & 8) + 2 * bp + (c & 1);
  }

  const int wslot = blockIdx.x * NWAVE + wave;

#pragma unroll 1
  for (int pi = 0; pi < PPW; ++pi) {
    const int g0 = (wslot * PPW + pi) * 2;   // 2 graphs: g0, g0+1
    if (g0 + 2 > p.gtot) break;

    // ---------------- pre-layer: a^T and e^T B-frags in registers ----------------
    short8_t af0, af1, ef0, ef1;
    {
      const float apv = p.ap[(g0 + (c >> 3)) * 4 + ((c >> 1) & 3)];
      const float e0v = p.ef[(g0 + (c >> 3)) * 16 + (c & 7) * 2];
      const float e1v = p.ef[(g0 + (c >> 3)) * 16 + (c & 7) * 2 + 1];
#pragma unroll
      for (int f = 0; f < 2; ++f) {
        const int base = 32 * f + 8 * qp;
        const float4 wa0 = *(const float4*)(sConst + CWPA + base);
        const float4 wa1 = *(const float4*)(sConst + CWPA + base + 4);
        const float4 ba0 = *(const float4*)(sConst + CBPA + base);
        const float4 ba1 = *(const float4*)(sConst + CBPA + base + 4);
        uint4 pa;
        pa.x = pk2(fmaxf(fmaf(apv, wa0.x, ba0.x), 0.f), fmaxf(fmaf(apv, wa0.y, ba0.y), 0.f));
        pa.y = pk2(fmaxf(fmaf(apv, wa0.z, ba0.z), 0.f), fmaxf(fmaf(apv, wa0.w, ba0.w), 0.f));
        pa.z = pk2(fmaxf(fmaf(apv, wa1.x, ba1.x), 0.f), fmaxf(fmaf(apv, wa1.y, ba1.y), 0.f));
        pa.w = pk2(fmaxf(fmaf(apv, wa1.z, ba1.z), 0.f), fmaxf(fmaf(apv, wa1.w, ba1.w), 0.f));
        const float4 w00 = *(const float4*)(sConst + CWPE + base);
        const float4 w01 = *(const float4*)(sConst + CWPE + base + 4);
        const float4 w10 = *(const float4*)(sConst + CWPE + 64 + base);
        const float4 w11 = *(const float4*)(sConst + CWPE + 64 + base + 4);
        const float4 be0 = *(const float4*)(sConst + CBPE + base);
        const float4 be1 = *(const float4*)(sConst + CBPE + base + 4);
        uint4 pe;
        pe.x = pk2(fmaxf(fmaf(e0v, w00.x, fmaf(e1v, w10.x, be0.x)), 0.f),
                   fmaxf(fmaf(e0v, w00.y, fmaf(e1v, w10.y, be0.y)), 0.f));
        pe.y = pk2(fmaxf(fmaf(e0v, w00.z, fmaf(e1v, w10.z, be0.z)), 0.f),
                   fmaxf(fmaf(e0v, w00.w, fmaf(e1v, w10.w, be0.w)), 0.f));
        pe.z = pk2(fmaxf(fmaf(e0v, w01.x, fmaf(e1v, w11.x, be1.x)), 0.f),
                   fmaxf(fmaf(e0v, w01.y, fmaf(e1v, w11.y, be1.y)), 0.f));
        pe.w = pk2(fmaxf(fmaf(e0v, w01.z, fmaf(e1v, w11.z, be1.z)), 0.f),
                   fmaxf(fmaf(e0v, w01.w, fmaf(e1v, w11.w, be1.w)), 0.f));
        if (f == 0) { af0 = __builtin_bit_cast(short8_t, pa); ef0 = __builtin_bit_cast(short8_t, pe); }
        else        { af1 = __builtin_bit_cast(short8_t, pa); ef1 = __builtin_bit_cast(short8_t, pe); }
      }
    }

    // ---- aP^T = w61[:64]^T a^T, b61 folded -> SoA LDS (iteration-invariant) ----
    {
      floatx4 acc[4];
      init0(acc);
      layerT<4>(acc, sW + OFF_W61, af0, af1, l);
#pragma unroll
      for (int t = 0; t < 4; ++t) {
        const float4 bv = *(const float4*)(sConst + CB61 + 16 * t + 4 * qp);
        sAP[(2 * t + 0) * 64 + l] = pk2(acc[t][0] + bv.x, acc[t][1] + bv.y);
        sAP[(2 * t + 1) * 64 + l] = pk2(acc[t][2] + bv.z, acc[t][3] + bv.w);
      }
    }

    // ---------------- 2 shared-weight update iterations ----------------
#pragma unroll 1
    for (int it = 0; it < 2; ++it) {
      // ---- mlp5 -> m1 (packed raw -> LDS; relu deferred to agg pkmax) ----
      {
        floatx4 acc[4];
        initB(acc, sConst + CB51, qp);
        layerT128(acc, sW + OFF_W51, af0, af1, ef0, ef1, l);
        short8_t t0, t1;
        packRf(t0, t1, acc);
        initB(acc, sConst + CB52, qp);
        layerT<2>(acc, sW + OFF_W52, t0, t1, l);
        packRf(t0, t1, acc);
        initB(acc, sConst + CB53, qp);
        layerT<2>(acc, sW + OFF_W53, t0, t1, l);
        packL(sM1, acc, l);
      }

      // ---- eP^T = w61[64:]^T e^T (raw pack -> LDS; b61 lives in sAP) ----
      {
        floatx4 acc[4];
        init0(acc);
        layerT<4>(acc, sW + OFF_W61 + 2 * 512, ef0, ef1, l);
        packL(sEP, acc, l);
      }

      // ---- mlp6 -> m2: 3 neighbor tiles, h from SoA LDS (own aP + nbr eP) ----
      u32 m2p[8];
#pragma unroll
      for (int j = 0; j < 3; ++j) {
        u32 hp[8];
#pragma unroll
        for (int i = 0; i < 8; ++i) {
          const u32 ap = sAP[i * 64 + l];
          const u32 ep = sEP[i * 64 + nb[j]];
          hp[i] = pk2(fmaxf(blo(ap) + blo(ep), 0.f),
                      fmaxf(bhi(ap) + bhi(ep), 0.f));
        }
        const short8_t h0 = mkf(hp[0], hp[2], hp[4], hp[6]);
        const short8_t h1 = mkf(hp[1], hp[3], hp[5], hp[7]);
        floatx4 acc[4];
        initB(acc, sConst + CB62, qp);
        layerT<2>(acc, sW + OFF_W62, h0, h1, l);
        short8_t t0, t1;
        packRf(t0, t1, acc);
        initB(acc, sConst + CB63, qp);
        layerT<2>(acc, sW + OFF_W63, t0, t1, l);
#pragma unroll
        for (int t = 0; t < 4; ++t) {
          const u32 c0 = pk2(acc[t][0], acc[t][1]);
          const u32 c1 = pk2(acc[t][2], acc[t][3]);
          m2p[2 * t + 0] = (j == 0) ? c0 : pkmax(m2p[2 * t + 0], c0);
          m2p[2 * t + 1] = (j == 0) ? c1 : pkmax(m2p[2 * t + 1], c1);
        }
      }

      // ---- agg = relu(max(m1[lane^1], m2)) + mlp7 ----
      {
        u32 agp[8];
#pragma unroll
        for (int i = 0; i < 8; ++i)
          agp[i] = pkmax(pkmax(sM1[i * 64 + (l ^ 1)], m2p[i]), 0u);
        const short8_t g0f = mkf(agp[0], agp[2], agp[4], agp[6]);
        const short8_t g1f = mkf(agp[1], agp[3], agp[5], agp[7]);
        floatx4 acc[4];
        initB(acc, sConst + CB71, qp);
        layerT128(acc, sW + OFF_W71, g0f, g1f, ef0, ef1, l);
        short8_t t0, t1;
        packRf(t0, t1, acc);
        initB(acc, sConst + CB72, qp);
        layerT<2>(acc, sW + OFF_W72, t0, t1, l);
        packRf(t0, t1, acc);
        initB(acc, sConst + CB73, qp);
        layerT<2>(acc, sW + OFF_W73, t0, t1, l);

        if (it == 0) {
          packRf(ef0, ef1, acc);   // new e^T stays in registers
        } else {
          // ---- post linear + per-(g,b) L2 row normalization ----
          float prr = 0.f, pii = 0.f;
#pragma unroll
          for (int t = 0; t < 4; ++t) {
            const float4 wr = *(const float4*)(sConst + CWPO + 16 * t + 4 * qp);
            const float4 wi = *(const float4*)(sConst + CWPO + 64 + 16 * t + 4 * qp);
            const float e0 = fmaxf(acc[t][0], 0.f);
            const float e1 = fmaxf(acc[t][1], 0.f);
            const float e2 = fmaxf(acc[t][2], 0.f);
            const float e3 = fmaxf(acc[t][3], 0.f);
            prr = fmaf(e0, wr.x, prr); pii = fmaf(e0, wi.x, pii);
            prr = fmaf(e1, wr.y, prr); pii = fmaf(e1, wi.y, pii);
            prr = fmaf(e2, wr.z, prr); pii = fmaf(e2, wi.z, pii);
            prr = fmaf(e3, wr.w, prr); pii = fmaf(e3, wi.w, pii);
          }
          // sum over the 4 lane quarters (same c)
          prr += __shfl_xor(prr, 16, 64); prr += __shfl_xor(prr, 32, 64);
          pii += __shfl_xor(pii, 16, 64); pii += __shfl_xor(pii, 32, 64);
          prr += sConst[CBPO];
          pii += sConst[CBPO + 1];
          // k-neighbor (row c^1) magnitudes
          const float prn = __uint_as_float(swz1(__float_as_uint(prr)));
          const float pin = __uint_as_float(swz1(__float_as_uint(pii)));
          const float n2 = prr * prr + pii * pii + prn * prn + pin * pin;
          if (qp < 2)
            p.out[g0 * 16 + c * 2 + qp] = ((qp == 0) ? prr : pii) / sqrtf(n2);
        }
      }
    }
  }
}

extern "C" void kernel_launch(void* const* d_in, const int* in_sizes, int n_in,
                              void* d_out, int out_size, void* d_ws, size_t ws_size,
                              hipStream_t stream) {
  Params p;
  p.ap    = (const float*)d_in[0];
  p.ef    = (const float*)d_in[1];
  p.wpa   = (const float*)d_in[2];  p.bpa   = (const float*)d_in[3];
  p.wpe   = (const float*)d_in[4];  p.bpe   = (const float*)d_in[5];
  p.w51   = (const float*)d_in[6];  p.b51   = (const float*)d_in[7];
  p.w52   = (const float*)d_in[8];  p.b52   = (const float*)d_in[9];
  p.w53   = (const float*)d_in[10]; p.b53   = (const float*)d_in[11];
  p.w61   = (const float*)d_in[12]; p.b61   = (const float*)d_in[13];
  p.w62   = (const float*)d_in[14]; p.b62   = (const float*)d_in[15];
  p.w63   = (const float*)d_in[16]; p.b63   = (const float*)d_in[17];
  p.w71   = (const float*)d_in[18]; p.b71   = (const float*)d_in[19];
  p.w72   = (const float*)d_in[20]; p.b72   = (const float*)d_in[21];
  p.w73   = (const float*)d_in[22]; p.b73   = (const float*)d_in[23];
  p.wpost = (const float*)d_in[24]; p.bpost = (const float*)d_in[25];
  p.out   = (float*)d_out;
  p.gtot  = in_sizes[0] / 4;  // G from ap_feat [G,B,1]

  hipLaunchKernelGGL(hetgnn_mfma, dim3(NBLK), dim3(512), 0, stream, p);
}

// Round 8
// 403.216 us; speedup vs baseline: 1.0691x; 1.0691x over previous
//
#include <hip/hip_runtime.h>

// HetGNN fused kernel, round 22: R21 body unchanged; occupancy attributes
// corrected for the toolchain's factor-2 waves-per-EU interpretation.
// Cross-round evidence: waves_per_eu(2)/(2,2) @512thr always caps VGPR at
// 128 (= 512/4, not the documented 512/2=256); waves_per_eu(4)/(4,4)
// @1024thr always caps at 64 (= 512/8, not 512/4). Every round is off by
// exactly 2x -- consistent with the budget heuristic counting wave32 slots
// (one wave64 = 2 slots). The transposed structure's true demand is
// ~200-280 regs; at a 128 budget ~150 dwords live in scratch, touched every
// iteration -> 1.24 GB HBM traffic -> 320 us (R19-R21).
// This round: amdgpu_waves_per_eu(1, 1) + __launch_bounds__(512, 1)
// -> effective budget 256. Occupancy is LDS-bound anyway (148.3 KB -> 1
// block/CU -> 2 waves/SIMD), so the declared min of 1 costs nothing.
// Single-variable experiment: if VGPR_Count rises and FETCH/WRITE collapse,
// the wave32 model is confirmed and the transposed design finally runs
// clean; if not, revert to the R18 base next round.

typedef unsigned short u16;
typedef unsigned int   u32;
typedef __attribute__((ext_vector_type(8))) short short8_t;
typedef __attribute__((ext_vector_type(2))) short short2v;
typedef __attribute__((ext_vector_type(4))) float floatx4;

// u16 offsets of each matrix's fragment block inside sW (fi*512 ordering).
// 96 frags: w51(16) w61(16) w71(16) w52(8) w53(8) w62(8) w63(8) w72(8) w73(8).
#define OFF_W51 0
#define OFF_W61 8192
#define OFF_W71 16384
#define OFF_W52 24576
#define OFF_W53 28672
#define OFF_W62 32768
#define OFF_W63 36864
#define OFF_W72 40960
#define OFF_W73 45056
#define WS_U16  49152

// f32 offsets inside the sConst LDS table.
// CB*: biases in NATURAL f_out order (read as float4 at 16t+4p).
// CWPO: wpost de-interleaved: [0..63] real, [64..127] imag (natural order).
// CWPA/CBPA/CBPE: 64 floats in pi-slot order (32f + 8p + j).
// CWPE: 2 x 64 in pi-slot order.
#define CB51 0
#define CB52 64
#define CB53 128
#define CB61 192
#define CB62 256
#define CB63 320
#define CB71 384
#define CB72 448
#define CB73 512
#define CWPO 576
#define CBPO 704
#define CWPA 768
#define CBPA 832
#define CWPE 896
#define CBPE 1024
#define CSZ  1088

// per-wave activation LDS: 3 SoA arrays x 8 elems x 64 lanes (u32)
#define AW_U32 1536

struct Params {
  const float *ap, *ef;
  const float *wpa, *bpa, *wpe, *bpe;
  const float *w51, *b51, *w52, *b52, *w53, *b53;
  const float *w61, *b61, *w62, *b62, *w63, *b63;
  const float *w71, *b71, *w72, *b72, *w73, *b73;
  const float *wpost, *bpost;
  float *out;
  int gtot;
};

// Pack two f32 to bf16 pair: round-half-up via +0x8000, then one byte-perm.
// Low half = first arg (= even slot j).
__device__ __forceinline__ u32 pk2(float a, float b) {
  const u32 ua = __float_as_uint(a) + 0x8000u;
  const u32 ub = __float_as_uint(b) + 0x8000u;
  return __builtin_amdgcn_perm(ub, ua, 0x07060302u);  // {ub[31:16], ua[31:16]}
}
__device__ __forceinline__ float blo(u32 v) { return __uint_as_float(v << 16); }
__device__ __forceinline__ float bhi(u32 v) { return __uint_as_float(v & 0xffff0000u); }
// packed int16 max: exact bf16-max in our use because the final max-with-0
// (deferred relu) dominates any mis-ordered negative intermediate.
__device__ __forceinline__ u32 pkmax(u32 a, u32 b) {
  const short2v r = __builtin_elementwise_max(__builtin_bit_cast(short2v, a),
                                              __builtin_bit_cast(short2v, b));
  return __builtin_bit_cast(u32, r);
}
// lane ^= 1 exchange (BitMode swizzle, xor=1), used in the epilogue only.
__device__ __forceinline__ u32 swz1(u32 x) {
  return (u32)__builtin_amdgcn_ds_swizzle((int)x, 0x041F);
}

__device__ __forceinline__ floatx4 mfma16(short8_t a, short8_t b, floatx4 c) {
  return __builtin_amdgcn_mfma_f32_16x16x32_bf16(a, b, c, 0, 0, 0);
}
__device__ __forceinline__ short8_t ldW(const u16* B, int f, int l) {
  return *(const short8_t*)(B + f * 512 + l * 8);
}
__device__ __forceinline__ short8_t mkf(u32 a, u32 b, u32 c, u32 d) {
  uint4 v; v.x = a; v.y = b; v.z = c; v.w = d;
  return __builtin_bit_cast(short8_t, v);
}

__device__ __forceinline__ void init0(floatx4* acc) {
#pragma unroll
  for (int t = 0; t < 4; ++t) { acc[t][0] = 0.f; acc[t][1] = 0.f; acc[t][2] = 0.f; acc[t][3] = 0.f; }
}
// Bias init: acc[t][r] = bias[16t + 4p + r] (f_out-indexed, broadcast b128).
__device__ __forceinline__ void initB(floatx4* acc, const float* cb, int qp) {
#pragma unroll
  for (int t = 0; t < 4; ++t) {
    const float4 b = *(const float4*)(cb + 16 * t + 4 * qp);
    acc[t][0] = b.x; acc[t][1] = b.y; acc[t][2] = b.z; acc[t][3] = b.w;
  }
}

// 64->64 layer, weights from LDS: frags (t*TS+0, t*TS+1).
template<int TS>
__device__ __forceinline__ void layerT(floatx4* acc, const u16* W,
                                       short8_t b0, short8_t b1, int l) {
#pragma unroll
  for (int t = 0; t < 4; ++t) {
    acc[t] = mfma16(ldW(W, t * TS + 0, l), b0, acc[t]);
    acc[t] = mfma16(ldW(W, t * TS + 1, l), b1, acc[t]);
  }
}
// K=128 layer (concat input = 4 B-frags), weights = 16 frags (t*4+h).
__device__ __forceinline__ void layerT128(floatx4* acc, const u16* W,
                                          short8_t f0, short8_t f1,
                                          short8_t f2, short8_t f3, int l) {
#pragma unroll
  for (int t = 0; t < 4; ++t) {
    acc[t] = mfma16(ldW(W, t * 4 + 0, l), f0, acc[t]);
    acc[t] = mfma16(ldW(W, t * 4 + 1, l), f1, acc[t]);
    acc[t] = mfma16(ldW(W, t * 4 + 2, l), f2, acc[t]);
    acc[t] = mfma16(ldW(W, t * 4 + 3, l), f3, acc[t]);
  }
}

// relu + pack acc -> next-layer B-frags (pi order: frag0 = pk01[t], frag1 = pk23[t]).
__device__ __forceinline__ void packRf(short8_t& f0, short8_t& f1, const floatx4* a) {
  uint4 u0, u1;
  u0.x = pk2(fmaxf(a[0][0], 0.f), fmaxf(a[0][1], 0.f));
  u1.x = pk2(fmaxf(a[0][2], 0.f), fmaxf(a[0][3], 0.f));
  u0.y = pk2(fmaxf(a[1][0], 0.f), fmaxf(a[1][1], 0.f));
  u1.y = pk2(fmaxf(a[1][2], 0.f), fmaxf(a[1][3], 0.f));
  u0.z = pk2(fmaxf(a[2][0], 0.f), fmaxf(a[2][1], 0.f));
  u1.z = pk2(fmaxf(a[2][2], 0.f), fmaxf(a[2][3], 0.f));
  u0.w = pk2(fmaxf(a[3][0], 0.f), fmaxf(a[3][1], 0.f));
  u1.w = pk2(fmaxf(a[3][2], 0.f), fmaxf(a[3][3], 0.f));
  f0 = __builtin_bit_cast(short8_t, u0);
  f1 = __builtin_bit_cast(short8_t, u1);
}
// raw pack (relu deferred) straight into SoA LDS: elem i at dst[i*64 + lane].
__device__ __forceinline__ void packL(u32* dst, const floatx4* a, int l) {
#pragma unroll
  for (int t = 0; t < 4; ++t) {
    dst[(2 * t + 0) * 64 + l] = pk2(a[t][0], a[t][1]);
    dst[(2 * t + 1) * 64 + l] = pk2(a[t][2], a[t][3]);
  }
}

#define NBLK 256
#define NWAVE 8
#define PPW  4   // 256 blk * 8 waves * 4 pairs = 8192 pairs = 16384 graphs

__global__ __launch_bounds__(512, 1)
__attribute__((amdgpu_waves_per_eu(1, 1)))
void hetgnn_mfma(Params p) {
  __shared__ __align__(16) u16   sW[WS_U16];            // 96 KB weights
  __shared__ __align__(16) u32   sAct[NWAVE * AW_U32];  // 48 KB: 8 x (aP|eP|m1)
  __shared__ __align__(16) float sConst[CSZ];           // 4.25 KB

  const int tid  = threadIdx.x;
  const int wave = tid >> 6;
  const int l    = tid & 63;
  const int qp   = l >> 4;   // lane quarter
  const int c    = l & 15;   // graph-row column: (g = c>>3, b = (c>>1)&3, k = c&1)

  // ---- stage + swizzle weights: f32 global -> bf16 A-frags in pi-k-order.
  //      A-frag (t,h): value(lane l, j) = W[kidx, 16t + (l&15)]
  //      K=64 mats:  kidx = 16*(j>>1) + 4*(l>>4) + 2*h + (j&1)
  //      K=128 mats: kidx = 64*(h>>1) + 16*(j>>1) + 4*(l>>4) + 2*(h&1) + (j&1)
  {
    for (int fi = wave; fi < 96; fi += NWAVE) {   // wave-uniform fi, 12/wave
      int t, h, mi;
      if (fi < 48) { mi = fi >> 4; const int loc = fi & 15; t = loc >> 2; h = loc & 3; }
      else { const int j2 = fi - 48; mi = 3 + (j2 >> 3); const int loc = j2 & 7; t = loc >> 1; h = loc & 1; }
      const float* W =
          (mi == 0) ? p.w51 : (mi == 1) ? p.w61 : (mi == 2) ? p.w71 :
          (mi == 3) ? p.w52 : (mi == 4) ? p.w53 : (mi == 5) ? p.w62 :
          (mi == 6) ? p.w63 : (mi == 7) ? p.w72 : p.w73;
      const int nn = 16 * t + c;
      float w[8];
#pragma unroll
      for (int jj = 0; jj < 8; ++jj) {
        const int kidx = (fi < 48)
            ? 64 * (h >> 1) + 16 * (jj >> 1) + 4 * qp + 2 * (h & 1) + (jj & 1)
            : 16 * (jj >> 1) + 4 * qp + 2 * h + (jj & 1);
        w[jj] = W[kidx * 64 + nn];
      }
      uint4 o;
      o.x = pk2(w[0], w[1]); o.y = pk2(w[2], w[3]);
      o.z = pk2(w[4], w[5]); o.w = pk2(w[6], w[7]);
      *(uint4*)(sW + fi * 512 + l * 8) = o;
    }
  }
  if (tid < 64) {
    // biases: natural f_out order
    sConst[CB51 + tid] = p.b51[tid];
    sConst[CB52 + tid] = p.b52[tid];
    sConst[CB53 + tid] = p.b53[tid];
    sConst[CB61 + tid] = p.b61[tid];
    sConst[CB62 + tid] = p.b62[tid];
    sConst[CB63 + tid] = p.b63[tid];
    sConst[CB71 + tid] = p.b71[tid];
    sConst[CB72 + tid] = p.b72[tid];
    sConst[CB73 + tid] = p.b73[tid];
    // wpost de-interleaved (natural order)
    sConst[CWPO + tid]      = p.wpost[2 * tid];
    sConst[CWPO + 64 + tid] = p.wpost[2 * tid + 1];
    // pre-layer weights/biases in pi-slot order: slot tid = 32f + 8p + j
    {
      const int f = tid >> 5, pp = (tid >> 3) & 3, jj = tid & 7;
      const int feat = 16 * (jj >> 1) + 4 * pp + 2 * f + (jj & 1);
      sConst[CWPA + tid] = p.wpa[feat];
      sConst[CBPA + tid] = p.bpa[feat];
      sConst[CBPE + tid] = p.bpe[feat];
    }
  }
  if (tid < 128) {
    const int s = tid & 63;
    const int f = s >> 5, pp = (s >> 3) & 3, jj = s & 7;
    const int feat = 16 * (jj >> 1) + 4 * pp + 2 * f + (jj & 1);
    sConst[CWPE + tid] = p.wpe[(tid >> 6) * 64 + feat];
  }
  if (tid < 2) sConst[CBPO + tid] = p.bpost[tid];
  __syncthreads();

  // per-wave SoA activation arrays (lane-private columns, no barriers needed)
  u32* sAP = sAct + wave * AW_U32;        // aP^T packed (b61 folded)
  u32* sEP = sAP + 512;                   // eP^T packed
  u32* sM1 = sAP + 1024;                  // m1 packed (raw, relu deferred)

  // neighbor row index inside the quarter, per j (3-lane collisions broadcast)
  const int b_ln = (c >> 1) & 3;
  int nb[3];
#pragma unroll
  for (int j = 0; j < 3; ++j) {
    const int bp = j + (j >= b_ln);
    nb[j] = (l & 48) + (c & 8) + 2 * bp + (c & 1);
  }

  const int wslot = blockIdx.x * NWAVE + wave;

#pragma unroll 1
  for (int pi = 0; pi < PPW; ++pi) {
    const int g0 = (wslot * PPW + pi) * 2;   // 2 graphs: g0, g0+1
    if (g0 + 2 > p.gtot) break;

    // ---------------- pre-layer: a^T and e^T B-frags in registers ----------------
    short8_t af0, af1, ef0, ef1;
    {
      const float apv = p.ap[(g0 + (c >> 3)) * 4 + ((c >> 1) & 3)];
      const float e0v = p.ef[(g0 + (c >> 3)) * 16 + (c & 7) * 2];
      const float e1v = p.ef[(g0 + (c >> 3)) * 16 + (c & 7) * 2 + 1];
#pragma unroll
      for (int f = 0; f < 2; ++f) {
        const int base = 32 * f + 8 * qp;
        const float4 wa0 = *(const float4*)(sConst + CWPA + base);
        const float4 wa1 = *(const float4*)(sConst + CWPA + base + 4);
        const float4 ba0 = *(const float4*)(sConst + CBPA + base);
        const float4 ba1 = *(const float4*)(sConst + CBPA + base + 4);
        uint4 pa;
        pa.x = pk2(fmaxf(fmaf(apv, wa0.x, ba0.x), 0.f), fmaxf(fmaf(apv, wa0.y, ba0.y), 0.f));
        pa.y = pk2(fmaxf(fmaf(apv, wa0.z, ba0.z), 0.f), fmaxf(fmaf(apv, wa0.w, ba0.w), 0.f));
        pa.z = pk2(fmaxf(fmaf(apv, wa1.x, ba1.x), 0.f), fmaxf(fmaf(apv, wa1.y, ba1.y), 0.f));
        pa.w = pk2(fmaxf(fmaf(apv, wa1.z, ba1.z), 0.f), fmaxf(fmaf(apv, wa1.w, ba1.w), 0.f));
        const float4 w00 = *(const float4*)(sConst + CWPE + base);
        const float4 w01 = *(const float4*)(sConst + CWPE + base + 4);
        const float4 w10 = *(const float4*)(sConst + CWPE + 64 + base);
        const float4 w11 = *(const float4*)(sConst + CWPE + 64 + base + 4);
        const float4 be0 = *(const float4*)(sConst + CBPE + base);
        const float4 be1 = *(const float4*)(sConst + CBPE + base + 4);
        uint4 pe;
        pe.x = pk2(fmaxf(fmaf(e0v, w00.x, fmaf(e1v, w10.x, be0.x)), 0.f),
                   fmaxf(fmaf(e0v, w00.y, fmaf(e1v, w10.y, be0.y)), 0.f));
        pe.y = pk2(fmaxf(fmaf(e0v, w00.z, fmaf(e1v, w10.z, be0.z)), 0.f),
                   fmaxf(fmaf(e0v, w00.w, fmaf(e1v, w10.w, be0.w)), 0.f));
        pe.z = pk2(fmaxf(fmaf(e0v, w01.x, fmaf(e1v, w11.x, be1.x)), 0.f),
                   fmaxf(fmaf(e0v, w01.y, fmaf(e1v, w11.y, be1.y)), 0.f));
        pe.w = pk2(fmaxf(fmaf(e0v, w01.z, fmaf(e1v, w11.z, be1.z)), 0.f),
                   fmaxf(fmaf(e0v, w01.w, fmaf(e1v, w11.w, be1.w)), 0.f));
        if (f == 0) { af0 = __builtin_bit_cast(short8_t, pa); ef0 = __builtin_bit_cast(short8_t, pe); }
        else        { af1 = __builtin_bit_cast(short8_t, pa); ef1 = __builtin_bit_cast(short8_t, pe); }
      }
    }

    // ---- aP^T = w61[:64]^T a^T, b61 folded -> SoA LDS (iteration-invariant) ----
    {
      floatx4 acc[4];
      init0(acc);
      layerT<4>(acc, sW + OFF_W61, af0, af1, l);
#pragma unroll
      for (int t = 0; t < 4; ++t) {
        const float4 bv = *(const float4*)(sConst + CB61 + 16 * t + 4 * qp);
        sAP[(2 * t + 0) * 64 + l] = pk2(acc[t][0] + bv.x, acc[t][1] + bv.y);
        sAP[(2 * t + 1) * 64 + l] = pk2(acc[t][2] + bv.z, acc[t][3] + bv.w);
      }
    }

    // ---------------- 2 shared-weight update iterations ----------------
#pragma unroll 1
    for (int it = 0; it < 2; ++it) {
      // ---- mlp5 -> m1 (packed raw -> LDS; relu deferred to agg pkmax) ----
      {
        floatx4 acc[4];
        initB(acc, sConst + CB51, qp);
        layerT128(acc, sW + OFF_W51, af0, af1, ef0, ef1, l);
        short8_t t0, t1;
        packRf(t0, t1, acc);
        initB(acc, sConst + CB52, qp);
        layerT<2>(acc, sW + OFF_W52, t0, t1, l);
        packRf(t0, t1, acc);
        initB(acc, sConst + CB53, qp);
        layerT<2>(acc, sW + OFF_W53, t0, t1, l);
        packL(sM1, acc, l);
      }

      // ---- eP^T = w61[64:]^T e^T (raw pack -> LDS; b61 lives in sAP) ----
      {
        floatx4 acc[4];
        init0(acc);
        layerT<4>(acc, sW + OFF_W61 + 2 * 512, ef0, ef1, l);
        packL(sEP, acc, l);
      }

      // ---- mlp6 -> m2: 3 neighbor tiles, h from SoA LDS (own aP + nbr eP) ----
      u32 m2p[8];
#pragma unroll
      for (int j = 0; j < 3; ++j) {
        u32 hp[8];
#pragma unroll
        for (int i = 0; i < 8; ++i) {
          const u32 ap = sAP[i * 64 + l];
          const u32 ep = sEP[i * 64 + nb[j]];
          hp[i] = pk2(fmaxf(blo(ap) + blo(ep), 0.f),
                      fmaxf(bhi(ap) + bhi(ep), 0.f));
        }
        const short8_t h0 = mkf(hp[0], hp[2], hp[4], hp[6]);
        const short8_t h1 = mkf(hp[1], hp[3], hp[5], hp[7]);
        floatx4 acc[4];
        initB(acc, sConst + CB62, qp);
        layerT<2>(acc, sW + OFF_W62, h0, h1, l);
        short8_t t0, t1;
        packRf(t0, t1, acc);
        initB(acc, sConst + CB63, qp);
        layerT<2>(acc, sW + OFF_W63, t0, t1, l);
#pragma unroll
        for (int t = 0; t < 4; ++t) {
          const u32 c0 = pk2(acc[t][0], acc[t][1]);
          const u32 c1 = pk2(acc[t][2], acc[t][3]);
          m2p[2 * t + 0] = (j == 0) ? c0 : pkmax(m2p[2 * t + 0], c0);
          m2p[2 * t + 1] = (j == 0) ? c1 : pkmax(m2p[2 * t + 1], c1);
        }
      }

      // ---- agg = relu(max(m1[lane^1], m2)) + mlp7 ----
      {
        u32 agp[8];
#pragma unroll
        for (int i = 0; i < 8; ++i)
          agp[i] = pkmax(pkmax(sM1[i * 64 + (l ^ 1)], m2p[i]), 0u);
        const short8_t g0f = mkf(agp[0], agp[2], agp[4], agp[6]);
        const short8_t g1f = mkf(agp[1], agp[3], agp[5], agp[7]);
        floatx4 acc[4];
        initB(acc, sConst + CB71, qp);
        layerT128(acc, sW + OFF_W71, g0f, g1f, ef0, ef1, l);
        short8_t t0, t1;
        packRf(t0, t1, acc);
        initB(acc, sConst + CB72, qp);
        layerT<2>(acc, sW + OFF_W72, t0, t1, l);
        packRf(t0, t1, acc);
        initB(acc, sConst + CB73, qp);
        layerT<2>(acc, sW + OFF_W73, t0, t1, l);

        if (it == 0) {
          packRf(ef0, ef1, acc);   // new e^T stays in registers
        } else {
          // ---- post linear + per-(g,b) L2 row normalization ----
          float prr = 0.f, pii = 0.f;
#pragma unroll
          for (int t = 0; t < 4; ++t) {
            const float4 wr = *(const float4*)(sConst + CWPO + 16 * t + 4 * qp);
            const float4 wi = *(const float4*)(sConst + CWPO + 64 + 16 * t + 4 * qp);
            const float e0 = fmaxf(acc[t][0], 0.f);
            const float e1 = fmaxf(acc[t][1], 0.f);
            const float e2 = fmaxf(acc[t][2], 0.f);
            const float e3 = fmaxf(acc[t][3], 0.f);
            prr = fmaf(e0, wr.x, prr); pii = fmaf(e0, wi.x, pii);
            prr = fmaf(e1, wr.y, prr); pii = fmaf(e1, wi.y, pii);
            prr = fmaf(e2, wr.z, prr); pii = fmaf(e2, wi.z, pii);
            prr = fmaf(e3, wr.w, prr); pii = fmaf(e3, wi.w, pii);
          }
          // sum over the 4 lane quarters (same c)
          prr += __shfl_xor(prr, 16, 64); prr += __shfl_xor(prr, 32, 64);
          pii += __shfl_xor(pii, 16, 64); pii += __shfl_xor(pii, 32, 64);
          prr += sConst[CBPO];
          pii += sConst[CBPO + 1];
          // k-neighbor (row c^1) magnitudes
          const float prn = __uint_as_float(swz1(__float_as_uint(prr)));
          const float pin = __uint_as_float(swz1(__float_as_uint(pii)));
          const float n2 = prr * prr + pii * pii + prn * prn + pin * pin;
          if (qp < 2)
            p.out[g0 * 16 + c * 2 + qp] = ((qp == 0) ? prr : pii) / sqrtf(n2);
        }
      }
    }
  }
}

extern "C" void kernel_launch(void* const* d_in, const int* in_sizes, int n_in,
                              void* d_out, int out_size, void* d_ws, size_t ws_size,
                              hipStream_t stream) {
  Params p;
  p.ap    = (const float*)d_in[0];
  p.ef    = (const float*)d_in[1];
  p.wpa   = (const float*)d_in[2];  p.bpa   = (const float*)d_in[3];
  p.wpe   = (const float*)d_in[4];  p.bpe   = (const float*)d_in[5];
  p.w51   = (const float*)d_in[6];  p.b51   = (const float*)d_in[7];
  p.w52   = (const float*)d_in[8];  p.b52   = (const float*)d_in[9];
  p.w53   = (const float*)d_in[10]; p.b53   = (const float*)d_in[11];
  p.w61   = (const float*)d_in[12]; p.b61   = (const float*)d_in[13];
  p.w62   = (const float*)d_in[14]; p.b62   = (const float*)d_in[15];
  p.w63   = (const float*)d_in[16]; p.b63   = (const float*)d_in[17];
  p.w71   = (const float*)d_in[18]; p.b71   = (const float*)d_in[19];
  p.w72   = (const float*)d_in[20]; p.b72   = (const float*)d_in[21];
  p.w73   = (const float*)d_in[22]; p.b73   = (const float*)d_in[23];
  p.wpost = (const float*)d_in[24]; p.bpost = (const float*)d_in[25];
  p.out   = (float*)d_out;
  p.gtot  = in_sizes[0] / 4;  // G from ap_feat [G,B,1]

  hipLaunchKernelGGL(hetgnn_mfma, dim3(NBLK), dim3(512), 0, stream, p);
}

// Round 9
// 166.887 us; speedup vs baseline: 2.5832x; 2.4161x over previous
//
#include <hip/hip_runtime.h>

// HetGNN fused kernel, round 23: R18 dual-chain base + skewed activation
// layout to eliminate the 8-way scatter bank conflicts.
// R19-R22 (transposed design) is abandoned: 4 attempts, zero movement on its
// 620 MB structural scratch traffic under the toolchain's hard 128-VGPR cap.
// R18 is the best clean structure (69.3 us/dispatch, FETCH 1.6 MB, no spill).
// Its measured waste: SQ_LDS_BANK_CONFLICT 5.37M/dispatch (~13% of cycles),
// proven to come from the sAct tiles (R19-22 read sW identically with 0).
// Scatter writes u16 at row*16B + col*2B; rows in one store differ by 16
// -> same bank every 8 rows -> 8-way conflict. Fix: skew the tile by 16 B
// per 8 rows: addr = row*16 + (row>>3)*16 + col*2.
//  - store bank-group = (i + 4q + (q>>1) + 2kk) mod 8 -> all 8 groups hit,
//    2 lanes/bank (same-dword halves) = free [m136];
//  - gathers stay 16B-aligned (skew adds multiples of 16 B);
//  - same bijection on write and read sides -> exact.
// BUF 1024->1152 u16, aPb 512->576; LDS ~158 KB, still 1 block/CU.
// All else identical to R18 (512 thr, dual chain, (2,2) attrs, 128 VGPR).

typedef unsigned short u16;
typedef unsigned int   u32;
typedef __attribute__((ext_vector_type(8))) short short8_t;
typedef __attribute__((ext_vector_type(2))) short short2v;
typedef __attribute__((ext_vector_type(4))) float floatx4;

// u16 offsets of each matrix's fragment block inside sW (fi*512 ordering).
// 96 frags: w51(16) w61(16) w71(16) w52(8) w53(8) w62(8) w63(8) w72(8) w73(8).
#define OFF_W51 0
#define OFF_W61 8192
#define OFF_W71 16384
#define OFF_W52 24576
#define OFF_W53 28672
#define OFF_W62 32768
#define OFF_W63 36864
#define OFF_W72 40960
#define OFF_W73 45056
#define WS_U16  49152

// f32 offsets inside the sConst LDS table.
#define CB51 0
#define CB52 64
#define CB53 128
#define CB61 192
#define CB62 256
#define CB63 320
#define CB71 384
#define CB72 448
#define CB73 512
#define CWPO 576
#define CBPO 704
#define CWPA 768
#define CBPA 832
#define CWPE 896
#define CBPE 1024
#define CSZ  1088

// skewed tile sizes: BUF = skr(128) = 1152 u16, aPb = skr(64) = 576 u16
#define BUF_U16 1152
#define APB_U16 576
#define PW_U16  3456   // 2 chains x (BUF | aPb)

struct Params {
  const float *ap, *ef;
  const float *wpa, *bpa, *wpe, *bpe;
  const float *w51, *b51, *w52, *b52, *w53, *b53;
  const float *w61, *b61, *w62, *b62, *w63, *b63;
  const float *w71, *b71, *w72, *b72, *w73, *b73;
  const float *wpost, *bpost;
  float *out;
  int gtot;
};

// Pack two f32 to bf16 pair: round-half-up via +0x8000, then one byte-perm.
__device__ __forceinline__ u32 pk2(float a, float b) {
  const u32 ua = __float_as_uint(a) + 0x8000u;
  const u32 ub = __float_as_uint(b) + 0x8000u;
  return __builtin_amdgcn_perm(ub, ua, 0x07060302u);  // {ub[31:16], ua[31:16]}
}
__device__ __forceinline__ float blo(u32 v) { return __uint_as_float(v << 16); }
__device__ __forceinline__ float bhi(u32 v) { return __uint_as_float(v & 0xffff0000u); }
// packed int16 max: exact bf16-max in our use because the final max-with-0
// (deferred relu) dominates any mis-ordered negative intermediate.
__device__ __forceinline__ u32 pkmax(u32 a, u32 b) {
  const short2v r = __builtin_elementwise_max(__builtin_bit_cast(short2v, a),
                                              __builtin_bit_cast(short2v, b));
  return __builtin_bit_cast(u32, r);
}
__device__ __forceinline__ u32 ror16(u32 x) { return (x >> 16) | (x << 16); }
__device__ __forceinline__ float sel4(int i, float x0, float x1, float x2, float x3) {
  const float lo = (i & 1) ? x1 : x0;
  const float hi = (i & 1) ? x3 : x2;
  return (i & 2) ? hi : lo;
}

// row -> u16 index of the row start in a skewed tile (16 B extra per 8 rows)
__device__ __forceinline__ int skr(int row) { return row * 8 + (row >> 3) * 8; }

__device__ __forceinline__ floatx4 mfma16(short8_t a, short8_t b, floatx4 c) {
  return __builtin_amdgcn_mfma_f32_16x16x32_bf16(a, b, c, 0, 0, 0);
}
// gather one full 16B row from a skewed tile
__device__ __forceinline__ short8_t ldAr(const u16* buf, int row) {
  return *(const short8_t*)(buf + skr(row));
}

// Dual-chain K=64 layer: each B fragment is loaded ONCE and feeds both
// chains; X/Y MFMAs alternate so the two acc dependency chains interleave.
template<int TSTRIDE>
__device__ __forceinline__ void layerK64R2(floatx4* aX, floatx4* aY,
                                           short8_t x0, short8_t x1,
                                           short8_t y0, short8_t y1,
                                           const u16* B, int l) {
#pragma unroll
  for (int t = 0; t < 4; ++t) {
    const short8_t b0 = *(const short8_t*)(B + (t * TSTRIDE + 0) * 512 + l * 8);
    const short8_t b1 = *(const short8_t*)(B + (t * TSTRIDE + 1) * 512 + l * 8);
    aX[t] = mfma16(x0, b0, aX[t]);
    aY[t] = mfma16(y0, b0, aY[t]);
    aX[t] = mfma16(x1, b1, aX[t]);
    aY[t] = mfma16(y1, b1, aY[t]);
  }
}

// Dual-chain K=128 layer (4 A-frags per chain), shared B loads.
__device__ __forceinline__ void layerK128R2(floatx4* aX, floatx4* aY,
                                            const short8_t* fx, const short8_t* fy,
                                            const u16* B, int l) {
#pragma unroll
  for (int t = 0; t < 4; ++t)
#pragma unroll
    for (int h = 0; h < 4; ++h) {
      const short8_t b = *(const short8_t*)(B + (t * 4 + h) * 512 + l * 8);
      aX[t] = mfma16(fx[h], b, aX[t]);
      aY[t] = mfma16(fy[h], b, aY[t]);
    }
}

// C-layout regs -> A-frag-swizzled bf16 LDS (with relu), skewed rows.
__device__ __forceinline__ void scatter_relu_bf16(u16* dst, const floatx4* acc, int q, int n) {
#pragma unroll
  for (int t = 0; t < 4; ++t) {
    const int kk = (t & 1) * 2 + (n >> 3);
    const int r0 = (t >> 1) * 64 + 4 * q + 16 * kk;
    u16* base = dst + (n & 7);
    const u32 v01 = pk2(fmaxf(acc[t][0], 0.f), fmaxf(acc[t][1], 0.f));
    const u32 v23 = pk2(fmaxf(acc[t][2], 0.f), fmaxf(acc[t][3], 0.f));
    base[skr(r0 + 0)] = (u16)v01;
    base[skr(r0 + 1)] = (u16)(v01 >> 16);
    base[skr(r0 + 2)] = (u16)v23;
    base[skr(r0 + 3)] = (u16)(v23 >> 16);
  }
}

// Same, no relu (eP can be negative).
__device__ __forceinline__ void scatter_bf16(u16* dst, const floatx4* acc, int q, int n) {
#pragma unroll
  for (int t = 0; t < 4; ++t) {
    const int kk = (t & 1) * 2 + (n >> 3);
    const int r0 = (t >> 1) * 64 + 4 * q + 16 * kk;
    u16* base = dst + (n & 7);
    const u32 v01 = pk2(acc[t][0], acc[t][1]);
    const u32 v23 = pk2(acc[t][2], acc[t][3]);
    base[skr(r0 + 0)] = (u16)v01;
    base[skr(r0 + 1)] = (u16)(v01 >> 16);
    base[skr(r0 + 2)] = (u16)v23;
    base[skr(r0 + 3)] = (u16)(v23 >> 16);
  }
}

// Packed src: src[2t+half] holds rows (4q+2half, 4q+2half+1).
__device__ __forceinline__ void scatter_pk(u16* dst, const u32* src, int q, int n) {
#pragma unroll
  for (int t = 0; t < 4; ++t) {
    const int kk = (t & 1) * 2 + (n >> 3);
    const int r0 = (t >> 1) * 64 + 4 * q + 16 * kk;
    u16* base = dst + (n & 7);
#pragma unroll
    for (int half = 0; half < 2; ++half) {
      const u32 v = src[2 * t + half];
      base[skr(r0 + 2 * half + 0)] = (u16)v;
      base[skr(r0 + 2 * half + 1)] = (u16)(v >> 16);
    }
  }
}

// aP dedup scatter (8 rows) WITH b61 pre-fold, skewed.
__device__ __forceinline__ void scatter_aP(u16* dst, const floatx4* acc, int q, int n,
                                           const float* cb61) {
#pragma unroll
  for (int t = 0; t < 4; ++t) {
    const int kk = (t & 1) * 2 + (n >> 3);
    const int r0 = (t >> 1) * 32 + 2 * q + 8 * kk;
    u16* base = dst + (n & 7);
    const float bv = cb61[16 * t + n];
    const u32 v = pk2(acc[t][0] + bv, acc[t][2] + bv);   // rows d=2q,2q+1
    base[skr(r0 + 0)] = (u16)v;
    base[skr(r0 + 1)] = (u16)(v >> 16);
  }
}

__device__ __forceinline__ void init_accL(floatx4* acc, const float* cb, int n) {
#pragma unroll
  for (int t = 0; t < 4; ++t) {
    const float b = cb[16 * t + n];
    floatx4 v; v[0] = b; v[1] = b; v[2] = b; v[3] = b;
    acc[t] = v;
  }
}
__device__ __forceinline__ void init_acc0(floatx4* acc) {
#pragma unroll
  for (int t = 0; t < 4; ++t) { acc[t][0] = 0.f; acc[t][1] = 0.f; acc[t][2] = 0.f; acc[t][3] = 0.f; }
}

struct frag2 { short8_t f0, f1; };

__device__ __forceinline__ frag2 make_a(float apv, int q, const float* sc) {
  frag2 r;
#pragma unroll
  for (int h = 0; h < 2; ++h) {
    const int fb = 32 * h + 8 * q;
    const float4 wa0 = *(const float4*)(sc + CWPA + fb);
    const float4 wa1 = *(const float4*)(sc + CWPA + fb + 4);
    const float4 ba0 = *(const float4*)(sc + CBPA + fb);
    const float4 ba1 = *(const float4*)(sc + CBPA + fb + 4);
    uint4 pa;
    pa.x = pk2(fmaxf(fmaf(apv, wa0.x, ba0.x), 0.f), fmaxf(fmaf(apv, wa0.y, ba0.y), 0.f));
    pa.y = pk2(fmaxf(fmaf(apv, wa0.z, ba0.z), 0.f), fmaxf(fmaf(apv, wa0.w, ba0.w), 0.f));
    pa.z = pk2(fmaxf(fmaf(apv, wa1.x, ba1.x), 0.f), fmaxf(fmaf(apv, wa1.y, ba1.y), 0.f));
    pa.w = pk2(fmaxf(fmaf(apv, wa1.z, ba1.z), 0.f), fmaxf(fmaf(apv, wa1.w, ba1.w), 0.f));
    if (h == 0) r.f0 = __builtin_bit_cast(short8_t, pa);
    else        r.f1 = __builtin_bit_cast(short8_t, pa);
  }
  return r;
}

// Pre-layer for one chain: a-frag + e-frags straight into registers.
__device__ __forceinline__ void prelayer(frag2& A, short8_t& e0, short8_t& e1,
                                         const Params& p, const float* sc,
                                         int g0, int q, int n) {
  const float apv = p.ap[(g0 + (n >> 3)) * 4 + ((n >> 1) & 3)];
  A = make_a(apv, q, sc);
  const float f0 = p.ef[(g0 + (n >> 3)) * 16 + (n & 7) * 2];
  const float f1 = p.ef[(g0 + (n >> 3)) * 16 + (n & 7) * 2 + 1];
#pragma unroll
  for (int h = 0; h < 2; ++h) {
    const int fb = 32 * h + 8 * q;
    const float4 w00 = *(const float4*)(sc + CWPE + fb);
    const float4 w01 = *(const float4*)(sc + CWPE + fb + 4);
    const float4 w10 = *(const float4*)(sc + CWPE + 64 + fb);
    const float4 w11 = *(const float4*)(sc + CWPE + 64 + fb + 4);
    const float4 be0 = *(const float4*)(sc + CBPE + fb);
    const float4 be1 = *(const float4*)(sc + CBPE + fb + 4);
    uint4 pe;
    pe.x = pk2(fmaxf(fmaf(f0, w00.x, fmaf(f1, w10.x, be0.x)), 0.f),
               fmaxf(fmaf(f0, w00.y, fmaf(f1, w10.y, be0.y)), 0.f));
    pe.y = pk2(fmaxf(fmaf(f0, w00.z, fmaf(f1, w10.z, be0.z)), 0.f),
               fmaxf(fmaf(f0, w00.w, fmaf(f1, w10.w, be0.w)), 0.f));
    pe.z = pk2(fmaxf(fmaf(f0, w01.x, fmaf(f1, w11.x, be1.x)), 0.f),
               fmaxf(fmaf(f0, w01.y, fmaf(f1, w11.y, be1.y)), 0.f));
    pe.w = pk2(fmaxf(fmaf(f0, w01.z, fmaf(f1, w11.z, be1.z)), 0.f),
               fmaxf(fmaf(f0, w01.w, fmaf(f1, w11.w, be1.w)), 0.f));
    if (h == 0) e0 = __builtin_bit_cast(short8_t, pe);
    else        e1 = __builtin_bit_cast(short8_t, pe);
  }
}

// Build the 3 neighbor-tile h fragments for one chain (skewed reads).
__device__ __forceinline__ void build_h(short8_t* hf0, short8_t* hf1,
                                        const u16* aPb, const u16* BUF,
                                        int q, int n) {
  const int d = n >> 1;
  const int b_ln = d & 3;
  const uint4 av0 = *(const uint4*)(aPb + skr(0 * 32 + d + 8 * q));
  const uint4 av1 = *(const uint4*)(aPb + skr(1 * 32 + d + 8 * q));
#pragma unroll
  for (int j = 0; j < 3; ++j) {
    const int bp = j + (j >= b_ln);   // j-th neighbor of b_ln
    const int re = (n & 8) + bp * 2 + (n & 1);
#pragma unroll
    for (int h = 0; h < 2; ++h) {
      const uint4 av = h ? av1 : av0;           // b61 already folded in
      const uint4 ev = *(const uint4*)(BUF + skr(h * 64 + re + 16 * q));
      uint4 ph;
      ph.x = pk2(fmaxf(blo(av.x) + blo(ev.x), 0.f),
                 fmaxf(bhi(av.x) + bhi(ev.x), 0.f));
      ph.y = pk2(fmaxf(blo(av.y) + blo(ev.y), 0.f),
                 fmaxf(bhi(av.y) + bhi(ev.y), 0.f));
      ph.z = pk2(fmaxf(blo(av.z) + blo(ev.z), 0.f),
                 fmaxf(bhi(av.z) + bhi(ev.z), 0.f));
      ph.w = pk2(fmaxf(blo(av.w) + blo(ev.w), 0.f),
                 fmaxf(bhi(av.w) + bhi(ev.w), 0.f));
      if (h == 0) hf0[j] = __builtin_bit_cast(short8_t, ph);
      else        hf1[j] = __builtin_bit_cast(short8_t, ph);
    }
  }
}

// Post linear + per-(g,b) L2 row normalization for one chain.
__device__ __forceinline__ void epilogue(const floatx4* acc3, const float* sc,
                                         float* out, int g0, int q, int n, bool ok) {
  float prr[4] = {0.f, 0.f, 0.f, 0.f}, pii[4] = {0.f, 0.f, 0.f, 0.f};
#pragma unroll
  for (int t = 0; t < 4; ++t) {
    const float wr = sc[CWPO + (16 * t + n) * 2];
    const float wi = sc[CWPO + (16 * t + n) * 2 + 1];
#pragma unroll
    for (int r = 0; r < 4; ++r) {
      const float e = fmaxf(acc3[t][r], 0.f);
      prr[r] = fmaf(e, wr, prr[r]);
      pii[r] = fmaf(e, wi, pii[r]);
    }
  }
  const float bpR = sc[CBPO], bpI = sc[CBPO + 1];
#pragma unroll
  for (int r = 0; r < 4; ++r) {
#pragma unroll
    for (int off = 1; off < 16; off <<= 1) {
      prr[r] += __shfl_xor(prr[r], off, 16);
      pii[r] += __shfl_xor(pii[r], off, 16);
    }
    prr[r] += bpR;
    pii[r] += bpI;
  }
  const int r = n >> 1, c = n & 1, rp = r ^ 1;
  const float pr_r  = sel4(r,  prr[0], prr[1], prr[2], prr[3]);
  const float pi_r  = sel4(r,  pii[0], pii[1], pii[2], pii[3]);
  const float pr_rp = sel4(rp, prr[0], prr[1], prr[2], prr[3]);
  const float pi_rp = sel4(rp, pii[0], pii[1], pii[2], pii[3]);
  const float num = c ? pi_r : pr_r;
  const float n2  = pr_r * pr_r + pi_r * pi_r + pr_rp * pr_rp + pi_rp * pi_rp;
  if (ok && n < 8) out[g0 * 16 + (4 * q + r) * 2 + c] = num / sqrtf(n2);
}

#define NBLK 256
#define NWAVE 8
#define PPW  2   // 256 blk * 8 waves * 2 chains * 2 = 8192 pairs = 16384 graphs

__global__ __launch_bounds__(512, 2)
__attribute__((amdgpu_waves_per_eu(2, 2)))
void hetgnn_mfma(Params p) {
  __shared__ __align__(16) u16   sW[WS_U16];            // 96 KB weights
  __shared__ __align__(16) u16   sAct[NWAVE * PW_U16];  // 54 KB: 8 x 2 x (BUF|aPb), skewed
  __shared__ __align__(16) float sConst[CSZ];           // 4.25 KB

  const int tid  = threadIdx.x;
  const int wave = tid >> 6;
  const int l    = tid & 63;
  const int q    = l >> 4;
  const int n    = l & 15;

  // ---- stage + swizzle weights (f32 global -> bf16 B-frag LDS), 96 frags.
  //      Branchless W select (runtime-indexed ptr array would go to scratch).
  {
    for (int fi = wave; fi < 96; fi += NWAVE) {   // wave-uniform fi, 12/wave
      int t, h, mi;
      if (fi < 48) { mi = fi >> 4; const int loc = fi & 15; t = loc >> 2; h = loc & 3; }
      else { const int j = fi - 48; mi = 3 + (j >> 3); const int loc = j & 7; t = loc >> 1; h = loc & 1; }
      const float* W =
          (mi == 0) ? p.w51 : (mi == 1) ? p.w61 : (mi == 2) ? p.w71 :
          (mi == 3) ? p.w52 : (mi == 4) ? p.w53 : (mi == 5) ? p.w62 :
          (mi == 6) ? p.w63 : (mi == 7) ? p.w72 : p.w73;
      const int nn = 16 * t + n;
      const int k0 = 32 * h + q * 8;
      float w[8];
#pragma unroll
      for (int j = 0; j < 8; ++j) w[j] = W[(k0 + j) * 64 + nn];
      uint4 o;
      o.x = pk2(w[0], w[1]); o.y = pk2(w[2], w[3]);
      o.z = pk2(w[4], w[5]); o.w = pk2(w[6], w[7]);
      *(uint4*)(sW + fi * 512 + l * 8) = o;
    }
  }
  if (tid < 64) {
    sConst[CB51 + tid] = p.b51[tid];
    sConst[CB52 + tid] = p.b52[tid];
    sConst[CB53 + tid] = p.b53[tid];
    sConst[CB61 + tid] = p.b61[tid];
    sConst[CB62 + tid] = p.b62[tid];
    sConst[CB63 + tid] = p.b63[tid];
    sConst[CB71 + tid] = p.b71[tid];
    sConst[CB72 + tid] = p.b72[tid];
    sConst[CB73 + tid] = p.b73[tid];
    sConst[CWPA + tid] = p.wpa[tid];
    sConst[CBPA + tid] = p.bpa[tid];
    sConst[CBPE + tid] = p.bpe[tid];
  }
  if (tid < 128) {
    sConst[CWPO + tid] = p.wpost[tid];
    sConst[CWPE + tid] = p.wpe[tid];
  }
  if (tid < 2) sConst[CBPO + tid] = p.bpost[tid];
  __syncthreads();

  u16* BUF0 = sAct + wave * PW_U16;   // chain X: T1 = eP = Eb alias (skewed)
  u16* aPb0 = BUF0 + BUF_U16;
  u16* BUF1 = aPb0 + APB_U16;         // chain Y
  u16* aPb1 = BUF1 + BUF_U16;

  const int wslot = blockIdx.x * NWAVE + wave;

#pragma unroll 1
  for (int pi = 0; pi < PPW; ++pi) {
    const int g0X = (wslot * 4 + 2 * pi) * 2;   // chain X: graphs g0X, g0X+1
    const int g0Y = g0X + 2;                    // chain Y: graphs g0Y, g0Y+1
    if (g0X + 2 > p.gtot) break;
    const bool okY = (g0Y + 2 <= p.gtot);
    const int gY  = okY ? g0Y : g0X;            // safe index for loads

    // ---------------- pre-layer, both chains ----------------
    frag2 AX, AY;
    short8_t ex0, ex1, ey0, ey1;
    prelayer(AX, ex0, ex1, p, sConst, g0X, q, n);
    prelayer(AY, ey0, ey1, p, sConst, gY,  q, n);

    // ---- aP = a @ w61[:64] (+ b61 pre-fold): iteration-invariant ----
    {
      floatx4 aaX[4], aaY[4];
      init_acc0(aaX); init_acc0(aaY);
      layerK64R2<4>(aaX, aaY, AX.f0, AX.f1, AY.f0, AY.f1, sW + OFF_W61, l);
      scatter_aP(aPb0, aaX, q, n, sConst + CB61);
      scatter_aP(aPb1, aaY, q, n, sConst + CB61);
    }

    // ---------------- 2 shared-weight update iterations ----------------
#pragma unroll 1
    for (int it = 0; it < 2; ++it) {
      if (it == 1) {
        ex0 = ldAr(BUF0, l); ex1 = ldAr(BUF0, 64 + l);   // new e from it0
        ey0 = ldAr(BUF1, l); ey1 = ldAr(BUF1, 64 + l);
      }

      // ---- mlp5 -> m1 (packed raw bf16; relu deferred to agg max) ----
      u32 m1pX[8], m1pY[8];
      {
        floatx4 aX[4], aY[4];
        init_accL(aX, sConst + CB51, n); init_accL(aY, sConst + CB51, n);
        const short8_t fx[4] = {AX.f0, AX.f1, ex0, ex1};
        const short8_t fy[4] = {AY.f0, AY.f1, ey0, ey1};
        layerK128R2(aX, aY, fx, fy, sW + OFF_W51, l);
        scatter_relu_bf16(BUF0, aX, q, n);
        scatter_relu_bf16(BUF1, aY, q, n);
        floatx4 bX[4], bY[4];
        init_accL(bX, sConst + CB52, n); init_accL(bY, sConst + CB52, n);
        {
          const short8_t gx0 = ldAr(BUF0, l), gx1 = ldAr(BUF0, 64 + l);
          const short8_t gy0 = ldAr(BUF1, l), gy1 = ldAr(BUF1, 64 + l);
          layerK64R2<2>(bX, bY, gx0, gx1, gy0, gy1, sW + OFF_W52, l);
        }
        scatter_relu_bf16(BUF0, bX, q, n);
        scatter_relu_bf16(BUF1, bY, q, n);
        floatx4 cX[4], cY[4];
        init_accL(cX, sConst + CB53, n); init_accL(cY, sConst + CB53, n);
        {
          const short8_t gx0 = ldAr(BUF0, l), gx1 = ldAr(BUF0, 64 + l);
          const short8_t gy0 = ldAr(BUF1, l), gy1 = ldAr(BUF1, 64 + l);
          layerK64R2<2>(cX, cY, gx0, gx1, gy0, gy1, sW + OFF_W53, l);
        }
#pragma unroll
        for (int t = 0; t < 4; ++t) {
          m1pX[2 * t + 0] = pk2(cX[t][0], cX[t][1]);
          m1pX[2 * t + 1] = pk2(cX[t][2], cX[t][3]);
          m1pY[2 * t + 0] = pk2(cY[t][0], cY[t][1]);
          m1pY[2 * t + 1] = pk2(cY[t][2], cY[t][3]);
        }
      }

      // ---- mlp6 -> m2: 3 neighbor-tiles; h-frags hoisted so eP (=BUF)
      //      dies before the first T1 (=BUF) scatter of the j-loop ----
      u32 m2pX[8], m2pY[8];
      {
        floatx4 eX[4], eY[4];
        init_acc0(eX); init_acc0(eY);
        layerK64R2<4>(eX, eY, ex0, ex1, ey0, ey1, sW + OFF_W61 + 2 * 512, l);
        scatter_bf16(BUF0, eX, q, n);   // eP
        scatter_bf16(BUF1, eY, q, n);

        short8_t hfX0[3], hfX1[3], hfY0[3], hfY1[3];
        build_h(hfX0, hfX1, aPb0, BUF0, q, n);
        build_h(hfY0, hfY1, aPb1, BUF1, q, n);

#pragma unroll
        for (int j = 0; j < 3; ++j) {
          floatx4 uX[4], uY[4];
          init_accL(uX, sConst + CB62, n); init_accL(uY, sConst + CB62, n);
          layerK64R2<2>(uX, uY, hfX0[j], hfX1[j], hfY0[j], hfY1[j], sW + OFF_W62, l);
          scatter_relu_bf16(BUF0, uX, q, n);
          scatter_relu_bf16(BUF1, uY, q, n);
          floatx4 vX[4], vY[4];
          init_accL(vX, sConst + CB63, n); init_accL(vY, sConst + CB63, n);
          {
            const short8_t gx0 = ldAr(BUF0, l), gx1 = ldAr(BUF0, 64 + l);
            const short8_t gy0 = ldAr(BUF1, l), gy1 = ldAr(BUF1, 64 + l);
            layerK64R2<2>(vX, vY, gx0, gx1, gy0, gy1, sW + OFF_W63, l);
          }
#pragma unroll
          for (int t = 0; t < 4; ++t) {
#pragma unroll
            for (int h = 0; h < 2; ++h) {
              const u32 cX = pk2(vX[t][2 * h], vX[t][2 * h + 1]);
              const u32 cY = pk2(vY[t][2 * h], vY[t][2 * h + 1]);
              m2pX[2 * t + h] = (j == 0) ? cX : pkmax(m2pX[2 * t + h], cX);
              m2pY[2 * t + h] = (j == 0) ? cY : pkmax(m2pY[2 * t + h], cY);
            }
          }
        }
      }

      // ---- agg = relu(max(m1[r^1], m2)) via pkmax-with-0, + mlp7 ----
      {
        u32 agX[8], agY[8];
#pragma unroll
        for (int i = 0; i < 8; ++i) {
          agX[i] = pkmax(pkmax(ror16(m1pX[i]), m2pX[i]), 0u);
          agY[i] = pkmax(pkmax(ror16(m1pY[i]), m2pY[i]), 0u);
        }
        scatter_pk(BUF0, agX, q, n);
        scatter_pk(BUF1, agY, q, n);
        floatx4 aX[4], aY[4];
        init_accL(aX, sConst + CB71, n); init_accL(aY, sConst + CB71, n);
        {
          const short8_t gx0 = ldAr(BUF0, l), gx1 = ldAr(BUF0, 64 + l);
          const short8_t gy0 = ldAr(BUF1, l), gy1 = ldAr(BUF1, 64 + l);
          const short8_t fx[4] = {gx0, gx1, ex0, ex1};
          const short8_t fy[4] = {gy0, gy1, ey0, ey1};
          layerK128R2(aX, aY, fx, fy, sW + OFF_W71, l);
        }
        scatter_relu_bf16(BUF0, aX, q, n);
        scatter_relu_bf16(BUF1, aY, q, n);
        floatx4 bX[4], bY[4];
        init_accL(bX, sConst + CB72, n); init_accL(bY, sConst + CB72, n);
        {
          const short8_t gx0 = ldAr(BUF0, l), gx1 = ldAr(BUF0, 64 + l);
          const short8_t gy0 = ldAr(BUF1, l), gy1 = ldAr(BUF1, 64 + l);
          layerK64R2<2>(bX, bY, gx0, gx1, gy0, gy1, sW + OFF_W72, l);
        }
        scatter_relu_bf16(BUF0, bX, q, n);
        scatter_relu_bf16(BUF1, bY, q, n);
        floatx4 cX[4], cY[4];
        init_accL(cX, sConst + CB73, n); init_accL(cY, sConst + CB73, n);
        {
          const short8_t gx0 = ldAr(BUF0, l), gx1 = ldAr(BUF0, 64 + l);
          const short8_t gy0 = ldAr(BUF1, l), gy1 = ldAr(BUF1, 64 + l);
          layerK64R2<2>(cX, cY, gx0, gx1, gy0, gy1, sW + OFF_W73, l);
        }

        if (it == 0) {
          scatter_relu_bf16(BUF0, cX, q, n);   // new e (cross-lane -> LDS)
          scatter_relu_bf16(BUF1, cY, q, n);
        } else {
          epilogue(cX, sConst, p.out, g0X, q, n, true);
          epilogue(cY, sConst, p.out, g0Y, q, n, okY);
        }
      }
    }
  }
}

extern "C" void kernel_launch(void* const* d_in, const int* in_sizes, int n_in,
                              void* d_out, int out_size, void* d_ws, size_t ws_size,
                              hipStream_t stream) {
  Params p;
  p.ap    = (const float*)d_in[0];
  p.ef    = (const float*)d_in[1];
  p.wpa   = (const float*)d_in[2];  p.bpa   = (const float*)d_in[3];
  p.wpe   = (const float*)d_in[4];  p.bpe   = (const float*)d_in[5];
  p.w51   = (const float*)d_in[6];  p.b51   = (const float*)d_in[7];
  p.w52   = (const float*)d_in[8];  p.b52   = (const float*)d_in[9];
  p.w53   = (const float*)d_in[10]; p.b53   = (const float*)d_in[11];
  p.w61   = (const float*)d_in[12]; p.b61   = (const float*)d_in[13];
  p.w62   = (const float*)d_in[14]; p.b62   = (const float*)d_in[15];
  p.w63   = (const float*)d_in[16]; p.b63   = (const float*)d_in[17];
  p.w71   = (const float*)d_in[18]; p.b71   = (const float*)d_in[19];
  p.w72   = (const float*)d_in[20]; p.b72   = (const float*)d_in[21];
  p.w73   = (const float*)d_in[22]; p.b73   = (const float*)d_in[23];
  p.wpost = (const float*)d_in[24]; p.bpost = (const float*)d_in[25];
  p.out   = (float*)d_out;
  p.gtot  = in_sizes[0] / 4;  // G from ap_feat [G,B,1]

  hipLaunchKernelGGL(hetgnn_mfma, dim3(NBLK), dim3(512), 0, stream, p);
}

// Round 11
// 157.228 us; speedup vs baseline: 2.7418x; 1.0614x over previous
//
#include <hip/hip_runtime.h>

// HetGNN fused kernel, round 25: R24 structure (pi0 k-permutation, row-pair
// u32 scatters, register k-swap) with the aliasing bug fixed.
// R24 failed (absmax 1.32) while the pi0 algebra verifies slot-by-slot and
// cvt_pk's lo=src0 order is HW-verified (m214v22). Diagnosis: R24's scatters
// stored via u32* while gathers loaded short-family short8_t -- clang TBAA
// treats those as non-aliasing, so the scheduler may hoist a layer's ds_read
// above the previous layer's ds_write (R23 used u16 stores = short family =
// ordered; it passed). Fixes:
//  1. pk2 (proven round-half-up pack) everywhere instead of asm cvtpk.
//  2. ldN loads via const uint4* (+bit_cast) -- same int family as u32 stores.
//  3. zero-instruction compiler fence asm volatile(""::: "memory") at the end
//     of every LDS-writing helper (covers the old eP/aPb u16->uint4 path too,
//     which was always technically UB).
// Structure kept from R24: pi0 slot (q,j) <-> feat (j&1)*16+4q+(j>>1) baked
// into weight staging + prelayer tables; T1/agg/new-e tiles hold packed
// feature-pairs -> 8 ds_write_b32 per scatter, writes 2 lanes/bank; m1 k-swap
// is a register index swap r^1; eP/aPb/h-build/w62 keep the R23 skewed path.
// Base: dual-chain, 512 thr, (2,2), 128 VGPR no-spill.

typedef unsigned short u16;
typedef unsigned int   u32;
typedef __attribute__((ext_vector_type(8))) short short8_t;
typedef __attribute__((ext_vector_type(2))) short short2v;
typedef __attribute__((ext_vector_type(4))) float floatx4;

#define LDSFENCE() asm volatile("" ::: "memory")

// u16 offsets of each matrix's fragment block inside sW (fi*512 ordering).
// 96 frags: w51(16) w61(16) w71(16) w52(8) w53(8) w62(8) w63(8) w72(8) w73(8).
#define OFF_W51 0
#define OFF_W61 8192
#define OFF_W71 16384
#define OFF_W52 24576
#define OFF_W53 28672
#define OFF_W62 32768
#define OFF_W63 36864
#define OFF_W72 40960
#define OFF_W73 45056
#define WS_U16  49152

// f32 offsets inside the sConst LDS table.
#define CB51 0
#define CB52 64
#define CB53 128
#define CB61 192
#define CB62 256
#define CB63 320
#define CB71 384
#define CB72 448
#define CB73 512
#define CWPO 576
#define CBPO 704
#define CWPA 768
#define CBPA 832
#define CWPE 896
#define CBPE 1024
#define CSZ  1088

// BUF: max(old-skew 1152 for eP, new-layout 1080); aPb: skr(64) = 576
#define BUF_U16 1152
#define APB_U16 576
#define PW_U16  3456   // 2 chains x (BUF | aPb)

struct Params {
  const float *ap, *ef;
  const float *wpa, *bpa, *wpe, *bpe;
  const float *w51, *b51, *w52, *b52, *w53, *b53;
  const float *w61, *b61, *w62, *b62, *w63, *b63;
  const float *w71, *b71, *w72, *b72, *w73, *b73;
  const float *wpost, *bpost;
  float *out;
  int gtot;
};

// Pack two f32 to bf16 pair: round-half-up via +0x8000, then one byte-perm.
// Low half = first arg.
__device__ __forceinline__ u32 pk2(float a, float b) {
  const u32 ua = __float_as_uint(a) + 0x8000u;
  const u32 ub = __float_as_uint(b) + 0x8000u;
  return __builtin_amdgcn_perm(ub, ua, 0x07060302u);  // {ub[31:16], ua[31:16]}
}
__device__ __forceinline__ float blo(u32 v) { return __uint_as_float(v << 16); }
__device__ __forceinline__ float bhi(u32 v) { return __uint_as_float(v & 0xffff0000u); }
// packed int16 max: exact bf16-max in our use because the final max-with-0
// (deferred relu) dominates any mis-ordered negative intermediate.
__device__ __forceinline__ u32 pkmax(u32 a, u32 b) {
  const short2v r = __builtin_elementwise_max(__builtin_bit_cast(short2v, a),
                                              __builtin_bit_cast(short2v, b));
  return __builtin_bit_cast(u32, r);
}
__device__ __forceinline__ float sel4(int i, float x0, float x1, float x2, float x3) {
  const float lo = (i & 1) ? x1 : x0;
  const float hi = (i & 1) ? x3 : x2;
  return (i & 2) ? hi : lo;
}

// old-layout skew (eP/aPb tiles): row -> u16 index, 16B extra per 8 rows
__device__ __forceinline__ int skr(int row) { return row * 8 + (row >> 3) * 8; }

__device__ __forceinline__ floatx4 mfma16(short8_t a, short8_t b, floatx4 c) {
  return __builtin_amdgcn_mfma_f32_16x16x32_bf16(a, b, c, 0, 0, 0);
}
// NEW-layout gather: row*16B + 16B skew per 16 rows. Loads through uint4
// (int family) so it orders against the u32 scatters under TBAA.
__device__ __forceinline__ short8_t ldN(const u16* buf, int row) {
  const uint4 v = *(const uint4*)(buf + row * 8 + (row >> 4) * 8);
  return __builtin_bit_cast(short8_t, v);
}

// Dual-chain K=64 layer: each B fragment is loaded ONCE and feeds both chains.
template<int TSTRIDE>
__device__ __forceinline__ void layerK64R2(floatx4* aX, floatx4* aY,
                                           short8_t x0, short8_t x1,
                                           short8_t y0, short8_t y1,
                                           const u16* B, int l) {
#pragma unroll
  for (int t = 0; t < 4; ++t) {
    const short8_t b0 = *(const short8_t*)(B + (t * TSTRIDE + 0) * 512 + l * 8);
    const short8_t b1 = *(const short8_t*)(B + (t * TSTRIDE + 1) * 512 + l * 8);
    aX[t] = mfma16(x0, b0, aX[t]);
    aY[t] = mfma16(y0, b0, aY[t]);
    aX[t] = mfma16(x1, b1, aX[t]);
    aY[t] = mfma16(y1, b1, aY[t]);
  }
}

// Dual-chain K=128 layer (4 A-frags per chain), shared B loads.
__device__ __forceinline__ void layerK128R2(floatx4* aX, floatx4* aY,
                                            const short8_t* fx, const short8_t* fy,
                                            const u16* B, int l) {
#pragma unroll
  for (int t = 0; t < 4; ++t)
#pragma unroll
    for (int h = 0; h < 4; ++h) {
      const short8_t b = *(const short8_t*)(B + (t * 4 + h) * 512 + l * 8);
      aX[t] = mfma16(fx[h], b, aX[t]);
      aY[t] = mfma16(fy[h], b, aY[t]);
    }
}

// NEW scatter: u32 (tp, r) from lane (q,n) -> row tp*64 + (n>>2)*16 + 4q + r,
// dword n&3. relu via packed pkmax0. 8 ds_write_b32, 2 lanes/bank.
__device__ __forceinline__ void scatterN_relu(u16* dst, const floatx4* acc, int q, int n) {
  u32* d32 = (u32*)dst;
  const int g = n >> 2, d = n & 3;
#pragma unroll
  for (int tp = 0; tp < 2; ++tp)
#pragma unroll
    for (int r = 0; r < 4; ++r) {
      const int row = tp * 64 + g * 16 + 4 * q + r;
      d32[row * 4 + (row >> 4) * 4 + d] =
          pkmax(pk2(acc[2 * tp + 0][r], acc[2 * tp + 1][r]), 0u);
    }
  LDSFENCE();
}
// NEW scatter of pre-packed u32s (v[tp*4+r]).
__device__ __forceinline__ void scatterN_u32(u16* dst, const u32* v, int q, int n) {
  u32* d32 = (u32*)dst;
  const int g = n >> 2, d = n & 3;
#pragma unroll
  for (int tp = 0; tp < 2; ++tp)
#pragma unroll
    for (int r = 0; r < 4; ++r) {
      const int row = tp * 64 + g * 16 + 4 * q + r;
      d32[row * 4 + (row >> 4) * 4 + d] = v[tp * 4 + r];
    }
  LDSFENCE();
}

// OLD-layout scatter (eP only), skewed u16 rows -- feeds build_h.
__device__ __forceinline__ void scatter_bf16(u16* dst, const floatx4* acc, int q, int n) {
#pragma unroll
  for (int t = 0; t < 4; ++t) {
    const int kk = (t & 1) * 2 + (n >> 3);
    const int r0 = (t >> 1) * 64 + 4 * q + 16 * kk;
    u16* base = dst + (n & 7);
    const u32 v01 = pk2(acc[t][0], acc[t][1]);
    const u32 v23 = pk2(acc[t][2], acc[t][3]);
    base[skr(r0 + 0)] = (u16)v01;
    base[skr(r0 + 1)] = (u16)(v01 >> 16);
    base[skr(r0 + 2)] = (u16)v23;
    base[skr(r0 + 3)] = (u16)(v23 >> 16);
  }
  LDSFENCE();
}

// aP dedup scatter (8 rows) WITH b61 pre-fold, skewed (old layout).
__device__ __forceinline__ void scatter_aP(u16* dst, const floatx4* acc, int q, int n,
                                           const float* cb61) {
#pragma unroll
  for (int t = 0; t < 4; ++t) {
    const int kk = (t & 1) * 2 + (n >> 3);
    const int r0 = (t >> 1) * 32 + 2 * q + 8 * kk;
    u16* base = dst + (n & 7);
    const float bv = cb61[16 * t + n];
    const u32 v = pk2(acc[t][0] + bv, acc[t][2] + bv);   // rows d=2q,2q+1
    base[skr(r0 + 0)] = (u16)v;
    base[skr(r0 + 1)] = (u16)(v >> 16);
  }
  LDSFENCE();
}

__device__ __forceinline__ void init_accL(floatx4* acc, const float* cb, int n) {
#pragma unroll
  for (int t = 0; t < 4; ++t) {
    const float b = cb[16 * t + n];
    floatx4 v; v[0] = b; v[1] = b; v[2] = b; v[3] = b;
    acc[t] = v;
  }
}
__device__ __forceinline__ void init_acc0(floatx4* acc) {
#pragma unroll
  for (int t = 0; t < 4; ++t) { acc[t][0] = 0.f; acc[t][1] = 0.f; acc[t][2] = 0.f; acc[t][3] = 0.f; }
}

struct frag2 { short8_t f0, f1; };

__device__ __forceinline__ frag2 make_a(float apv, int q, const float* sc) {
  frag2 r;
#pragma unroll
  for (int h = 0; h < 2; ++h) {
    const int fb = 32 * h + 8 * q;
    const float4 wa0 = *(const float4*)(sc + CWPA + fb);
    const float4 wa1 = *(const float4*)(sc + CWPA + fb + 4);
    const float4 ba0 = *(const float4*)(sc + CBPA + fb);
    const float4 ba1 = *(const float4*)(sc + CBPA + fb + 4);
    uint4 pa;
    pa.x = pk2(fmaxf(fmaf(apv, wa0.x, ba0.x), 0.f), fmaxf(fmaf(apv, wa0.y, ba0.y), 0.f));
    pa.y = pk2(fmaxf(fmaf(apv, wa0.z, ba0.z), 0.f), fmaxf(fmaf(apv, wa0.w, ba0.w), 0.f));
    pa.z = pk2(fmaxf(fmaf(apv, wa1.x, ba1.x), 0.f), fmaxf(fmaf(apv, wa1.y, ba1.y), 0.f));
    pa.w = pk2(fmaxf(fmaf(apv, wa1.z, ba1.z), 0.f), fmaxf(fmaf(apv, wa1.w, ba1.w), 0.f));
    if (h == 0) r.f0 = __builtin_bit_cast(short8_t, pa);
    else        r.f1 = __builtin_bit_cast(short8_t, pa);
  }
  return r;
}

// Pre-layer for one chain (tables are pi0-permuted at staging).
__device__ __forceinline__ void prelayer(frag2& A, short8_t& e0, short8_t& e1,
                                         const Params& p, const float* sc,
                                         int g0, int q, int n) {
  const float apv = p.ap[(g0 + (n >> 3)) * 4 + ((n >> 1) & 3)];
  A = make_a(apv, q, sc);
  const float f0 = p.ef[(g0 + (n >> 3)) * 16 + (n & 7) * 2];
  const float f1 = p.ef[(g0 + (n >> 3)) * 16 + (n & 7) * 2 + 1];
#pragma unroll
  for (int h = 0; h < 2; ++h) {
    const int fb = 32 * h + 8 * q;
    const float4 w00 = *(const float4*)(sc + CWPE + fb);
    const float4 w01 = *(const float4*)(sc + CWPE + fb + 4);
    const float4 w10 = *(const float4*)(sc + CWPE + 64 + fb);
    const float4 w11 = *(const float4*)(sc + CWPE + 64 + fb + 4);
    const float4 be0 = *(const float4*)(sc + CBPE + fb);
    const float4 be1 = *(const float4*)(sc + CBPE + fb + 4);
    uint4 pe;
    pe.x = pk2(fmaxf(fmaf(f0, w00.x, fmaf(f1, w10.x, be0.x)), 0.f),
               fmaxf(fmaf(f0, w00.y, fmaf(f1, w10.y, be0.y)), 0.f));
    pe.y = pk2(fmaxf(fmaf(f0, w00.z, fmaf(f1, w10.z, be0.z)), 0.f),
               fmaxf(fmaf(f0, w00.w, fmaf(f1, w10.w, be0.w)), 0.f));
    pe.z = pk2(fmaxf(fmaf(f0, w01.x, fmaf(f1, w11.x, be1.x)), 0.f),
               fmaxf(fmaf(f0, w01.y, fmaf(f1, w11.y, be1.y)), 0.f));
    pe.w = pk2(fmaxf(fmaf(f0, w01.z, fmaf(f1, w11.z, be1.z)), 0.f),
               fmaxf(fmaf(f0, w01.w, fmaf(f1, w11.w, be1.w)), 0.f));
    if (h == 0) e0 = __builtin_bit_cast(short8_t, pe);
    else        e1 = __builtin_bit_cast(short8_t, pe);
  }
}

// Build the 3 neighbor-tile h fragments for one chain (old skewed layout).
__device__ __forceinline__ void build_h(short8_t* hf0, short8_t* hf1,
                                        const u16* aPb, const u16* BUF,
                                        int q, int n) {
  const int d = n >> 1;
  const int b_ln = d & 3;
  const uint4 av0 = *(const uint4*)(aPb + skr(0 * 32 + d + 8 * q));
  const uint4 av1 = *(const uint4*)(aPb + skr(1 * 32 + d + 8 * q));
#pragma unroll
  for (int j = 0; j < 3; ++j) {
    const int bp = j + (j >= b_ln);   // j-th neighbor of b_ln
    const int re = (n & 8) + bp * 2 + (n & 1);
#pragma unroll
    for (int h = 0; h < 2; ++h) {
      const uint4 av = h ? av1 : av0;           // b61 already folded in
      const uint4 ev = *(const uint4*)(BUF + skr(h * 64 + re + 16 * q));
      uint4 ph;
      ph.x = pk2(fmaxf(blo(av.x) + blo(ev.x), 0.f),
                 fmaxf(bhi(av.x) + bhi(ev.x), 0.f));
      ph.y = pk2(fmaxf(blo(av.y) + blo(ev.y), 0.f),
                 fmaxf(bhi(av.y) + bhi(ev.y), 0.f));
      ph.z = pk2(fmaxf(blo(av.z) + blo(ev.z), 0.f),
                 fmaxf(bhi(av.z) + bhi(ev.z), 0.f));
      ph.w = pk2(fmaxf(blo(av.w) + blo(ev.w), 0.f),
                 fmaxf(bhi(av.w) + bhi(ev.w), 0.f));
      if (h == 0) hf0[j] = __builtin_bit_cast(short8_t, ph);
      else        hf1[j] = __builtin_bit_cast(short8_t, ph);
    }
  }
}

// Post linear + per-(g,b) L2 row normalization for one chain.
__device__ __forceinline__ void epilogue(const floatx4* acc3, const float* sc,
                                         float* out, int g0, int q, int n, bool ok) {
  float prr[4] = {0.f, 0.f, 0.f, 0.f}, pii[4] = {0.f, 0.f, 0.f, 0.f};
#pragma unroll
  for (int t = 0; t < 4; ++t) {
    const float wr = sc[CWPO + (16 * t + n) * 2];
    const float wi = sc[CWPO + (16 * t + n) * 2 + 1];
#pragma unroll
    for (int r = 0; r < 4; ++r) {
      const float e = fmaxf(acc3[t][r], 0.f);
      prr[r] = fmaf(e, wr, prr[r]);
      pii[r] = fmaf(e, wi, pii[r]);
    }
  }
  const float bpR = sc[CBPO], bpI = sc[CBPO + 1];
#pragma unroll
  for (int r = 0; r < 4; ++r) {
#pragma unroll
    for (int off = 1; off < 16; off <<= 1) {
      prr[r] += __shfl_xor(prr[r], off, 16);
      pii[r] += __shfl_xor(pii[r], off, 16);
    }
    prr[r] += bpR;
    pii[r] += bpI;
  }
  const int r = n >> 1, c = n & 1, rp = r ^ 1;
  const float pr_r  = sel4(r,  prr[0], prr[1], prr[2], prr[3]);
  const float pi_r  = sel4(r,  pii[0], pii[1], pii[2], pii[3]);
  const float pr_rp = sel4(rp, prr[0], prr[1], prr[2], prr[3]);
  const float pi_rp = sel4(rp, pii[0], pii[1], pii[2], pii[3]);
  const float num = c ? pi_r : pr_r;
  const float n2  = pr_r * pr_r + pi_r * pi_r + pr_rp * pr_rp + pi_rp * pi_rp;
  if (ok && n < 8) out[g0 * 16 + (4 * q + r) * 2 + c] = num / sqrtf(n2);
}

#define NBLK 256
#define NWAVE 8
#define PPW  2   // 256 blk * 8 waves * 2 chains * 2 = 8192 pairs = 16384 graphs

__global__ __launch_bounds__(512, 2)
__attribute__((amdgpu_waves_per_eu(2, 2)))
void hetgnn_mfma(Params p) {
  __shared__ __align__(16) u16   sW[WS_U16];            // 96 KB weights
  __shared__ __align__(16) u16   sAct[NWAVE * PW_U16];  // 54 KB: 8 x 2 x (BUF|aPb)
  __shared__ __align__(16) float sConst[CSZ];           // 4.25 KB

  const int tid  = threadIdx.x;
  const int wave = tid >> 6;
  const int l    = tid & 63;
  const int q    = l >> 4;
  const int n    = l & 15;

  // ---- stage + swizzle weights (f32 global -> bf16 B-frag LDS), 96 frags.
  //      pi0 k-order for all mats except w62 (which consumes hand-built h).
  {
    for (int fi = wave; fi < 96; fi += NWAVE) {   // wave-uniform fi, 12/wave
      int t, h, mi;
      if (fi < 48) { mi = fi >> 4; const int loc = fi & 15; t = loc >> 2; h = loc & 3; }
      else { const int j = fi - 48; mi = 3 + (j >> 3); const int loc = j & 7; t = loc >> 1; h = loc & 1; }
      const float* W =
          (mi == 0) ? p.w51 : (mi == 1) ? p.w61 : (mi == 2) ? p.w71 :
          (mi == 3) ? p.w52 : (mi == 4) ? p.w53 : (mi == 5) ? p.w62 :
          (mi == 6) ? p.w63 : (mi == 7) ? p.w72 : p.w73;
      const int nn = 16 * t + n;
      float w[8];
#pragma unroll
      for (int jj = 0; jj < 8; ++jj) {
        int kidx;
        if (fi < 48)      kidx = 64 * (h >> 1) + 32 * (h & 1) + (jj & 1) * 16 + 4 * q + (jj >> 1);
        else if (mi == 5) kidx = 32 * h + 8 * q + jj;   // w62: old h-frag order
        else              kidx = 32 * h + (jj & 1) * 16 + 4 * q + (jj >> 1);
        w[jj] = W[kidx * 64 + nn];
      }
      uint4 o;
      o.x = pk2(w[0], w[1]); o.y = pk2(w[2], w[3]);
      o.z = pk2(w[4], w[5]); o.w = pk2(w[6], w[7]);
      *(uint4*)(sW + fi * 512 + l * 8) = o;
    }
  }
  if (tid < 64) {
    sConst[CB51 + tid] = p.b51[tid];
    sConst[CB52 + tid] = p.b52[tid];
    sConst[CB53 + tid] = p.b53[tid];
    sConst[CB61 + tid] = p.b61[tid];
    sConst[CB62 + tid] = p.b62[tid];
    sConst[CB63 + tid] = p.b63[tid];
    sConst[CB71 + tid] = p.b71[tid];
    sConst[CB72 + tid] = p.b72[tid];
    sConst[CB73 + tid] = p.b73[tid];
    // pre-layer tables permuted to pi0 slot order:
    // slot s holds feat = 32*(s>>5) + (s&1)*16 + 4*((s>>3)&3) + ((s>>1)&3)
    const int feat = 32 * (tid >> 5) + (tid & 1) * 16 + 4 * ((tid >> 3) & 3) + ((tid >> 1) & 3);
    sConst[CWPA + tid] = p.wpa[feat];
    sConst[CBPA + tid] = p.bpa[feat];
    sConst[CBPE + tid] = p.bpe[feat];
  }
  if (tid < 128) {
    sConst[CWPO + tid] = p.wpost[tid];
    const int s = tid & 63;
    const int feat = 32 * (s >> 5) + (s & 1) * 16 + 4 * ((s >> 3) & 3) + ((s >> 1) & 3);
    sConst[CWPE + tid] = p.wpe[(tid >> 6) * 64 + feat];
  }
  if (tid < 2) sConst[CBPO + tid] = p.bpost[tid];
  __syncthreads();

  u16* BUF0 = sAct + wave * PW_U16;   // chain X: T1 = eP = Eb alias
  u16* aPb0 = BUF0 + BUF_U16;
  u16* BUF1 = aPb0 + APB_U16;         // chain Y
  u16* aPb1 = BUF1 + BUF_U16;

  const int wslot = blockIdx.x * NWAVE + wave;

#pragma unroll 1
  for (int pi = 0; pi < PPW; ++pi) {
    const int g0X = (wslot * 4 + 2 * pi) * 2;   // chain X: graphs g0X, g0X+1
    const int g0Y = g0X + 2;                    // chain Y: graphs g0Y, g0Y+1
    if (g0X + 2 > p.gtot) break;
    const bool okY = (g0Y + 2 <= p.gtot);
    const int gY  = okY ? g0Y : g0X;            // safe index for loads

    // ---------------- pre-layer, both chains ----------------
    frag2 AX, AY;
    short8_t ex0, ex1, ey0, ey1;
    prelayer(AX, ex0, ex1, p, sConst, g0X, q, n);
    prelayer(AY, ey0, ey1, p, sConst, gY,  q, n);

    // ---- aP = a @ w61[:64] (+ b61 pre-fold): iteration-invariant ----
    {
      floatx4 aaX[4], aaY[4];
      init_acc0(aaX); init_acc0(aaY);
      layerK64R2<4>(aaX, aaY, AX.f0, AX.f1, AY.f0, AY.f1, sW + OFF_W61, l);
      scatter_aP(aPb0, aaX, q, n, sConst + CB61);
      scatter_aP(aPb1, aaY, q, n, sConst + CB61);
    }

    // ---------------- 2 shared-weight update iterations ----------------
#pragma unroll 1
    for (int it = 0; it < 2; ++it) {
      if (it == 1) {
        ex0 = ldN(BUF0, l); ex1 = ldN(BUF0, 64 + l);   // new e from it0
        ey0 = ldN(BUF1, l); ey1 = ldN(BUF1, 64 + l);
      }

      // ---- mlp5 -> m1 (tpair-packed raw bf16; relu deferred to agg) ----
      u32 m1pX[8], m1pY[8];
      {
        floatx4 aX[4], aY[4];
        init_accL(aX, sConst + CB51, n); init_accL(aY, sConst + CB51, n);
        const short8_t fx[4] = {AX.f0, AX.f1, ex0, ex1};
        const short8_t fy[4] = {AY.f0, AY.f1, ey0, ey1};
        layerK128R2(aX, aY, fx, fy, sW + OFF_W51, l);
        scatterN_relu(BUF0, aX, q, n);
        scatterN_relu(BUF1, aY, q, n);
        floatx4 bX[4], bY[4];
        init_accL(bX, sConst + CB52, n); init_accL(bY, sConst + CB52, n);
        {
          const short8_t gx0 = ldN(BUF0, l), gx1 = ldN(BUF0, 64 + l);
          const short8_t gy0 = ldN(BUF1, l), gy1 = ldN(BUF1, 64 + l);
          layerK64R2<2>(bX, bY, gx0, gx1, gy0, gy1, sW + OFF_W52, l);
        }
        scatterN_relu(BUF0, bX, q, n);
        scatterN_relu(BUF1, bY, q, n);
        floatx4 cX[4], cY[4];
        init_accL(cX, sConst + CB53, n); init_accL(cY, sConst + CB53, n);
        {
          const short8_t gx0 = ldN(BUF0, l), gx1 = ldN(BUF0, 64 + l);
          const short8_t gy0 = ldN(BUF1, l), gy1 = ldN(BUF1, 64 + l);
          layerK64R2<2>(cX, cY, gx0, gx1, gy0, gy1, sW + OFF_W53, l);
        }
#pragma unroll
        for (int tp = 0; tp < 2; ++tp)
#pragma unroll
          for (int r = 0; r < 4; ++r) {
            m1pX[tp * 4 + r] = pk2(cX[2 * tp][r], cX[2 * tp + 1][r]);
            m1pY[tp * 4 + r] = pk2(cY[2 * tp][r], cY[2 * tp + 1][r]);
          }
      }

      // ---- mlp6 -> m2: 3 neighbor-tiles; h-frags hoisted so eP (=BUF)
      //      dies before the first T1 (=BUF) scatter of the j-loop ----
      u32 m2pX[8], m2pY[8];
      {
        floatx4 eX[4], eY[4];
        init_acc0(eX); init_acc0(eY);
        layerK64R2<4>(eX, eY, ex0, ex1, ey0, ey1, sW + OFF_W61 + 2 * 512, l);
        scatter_bf16(BUF0, eX, q, n);   // eP (old skewed layout, feeds build_h)
        scatter_bf16(BUF1, eY, q, n);

        short8_t hfX0[3], hfX1[3], hfY0[3], hfY1[3];
        build_h(hfX0, hfX1, aPb0, BUF0, q, n);
        build_h(hfY0, hfY1, aPb1, BUF1, q, n);

#pragma unroll
        for (int j = 0; j < 3; ++j) {
          floatx4 uX[4], uY[4];
          init_accL(uX, sConst + CB62, n); init_accL(uY, sConst + CB62, n);
          layerK64R2<2>(uX, uY, hfX0[j], hfX1[j], hfY0[j], hfY1[j], sW + OFF_W62, l);
          scatterN_relu(BUF0, uX, q, n);
          scatterN_relu(BUF1, uY, q, n);
          floatx4 vX[4], vY[4];
          init_accL(vX, sConst + CB63, n); init_accL(vY, sConst + CB63, n);
          {
            const short8_t gx0 = ldN(BUF0, l), gx1 = ldN(BUF0, 64 + l);
            const short8_t gy0 = ldN(BUF1, l), gy1 = ldN(BUF1, 64 + l);
            layerK64R2<2>(vX, vY, gx0, gx1, gy0, gy1, sW + OFF_W63, l);
          }
#pragma unroll
          for (int tp = 0; tp < 2; ++tp)
#pragma unroll
            for (int r = 0; r < 4; ++r) {
              const u32 cXv = pk2(vX[2 * tp][r], vX[2 * tp + 1][r]);
              const u32 cYv = pk2(vY[2 * tp][r], vY[2 * tp + 1][r]);
              const int i = tp * 4 + r;
              m2pX[i] = (j == 0) ? cXv : pkmax(m2pX[i], cXv);
              m2pY[i] = (j == 0) ? cYv : pkmax(m2pY[i], cYv);
            }
        }
      }

      // ---- agg = relu(max(m1[k^1], m2)): k-swap is a register index swap ----
      {
        u32 agX[8], agY[8];
#pragma unroll
        for (int tp = 0; tp < 2; ++tp)
#pragma unroll
          for (int r = 0; r < 4; ++r) {
            const int i = tp * 4 + r;
            agX[i] = pkmax(pkmax(m1pX[tp * 4 + (r ^ 1)], m2pX[i]), 0u);
            agY[i] = pkmax(pkmax(m1pY[tp * 4 + (r ^ 1)], m2pY[i]), 0u);
          }
        scatterN_u32(BUF0, agX, q, n);
        scatterN_u32(BUF1, agY, q, n);
        floatx4 aX[4], aY[4];
        init_accL(aX, sConst + CB71, n); init_accL(aY, sConst + CB71, n);
        {
          const short8_t gx0 = ldN(BUF0, l), gx1 = ldN(BUF0, 64 + l);
          const short8_t gy0 = ldN(BUF1, l), gy1 = ldN(BUF1, 64 + l);
          const short8_t fx[4] = {gx0, gx1, ex0, ex1};
          const short8_t fy[4] = {gy0, gy1, ey0, ey1};
          layerK128R2(aX, aY, fx, fy, sW + OFF_W71, l);
        }
        scatterN_relu(BUF0, aX, q, n);
        scatterN_relu(BUF1, aY, q, n);
        floatx4 bX[4], bY[4];
        init_accL(bX, sConst + CB72, n); init_accL(bY, sConst + CB72, n);
        {
          const short8_t gx0 = ldN(BUF0, l), gx1 = ldN(BUF0, 64 + l);
          const short8_t gy0 = ldN(BUF1, l), gy1 = ldN(BUF1, 64 + l);
          layerK64R2<2>(bX, bY, gx0, gx1, gy0, gy1, sW + OFF_W72, l);
        }
        scatterN_relu(BUF0, bX, q, n);
        scatterN_relu(BUF1, bY, q, n);
        floatx4 cX[4], cY[4];
        init_accL(cX, sConst + CB73, n); init_accL(cY, sConst + CB73, n);
        {
          const short8_t gx0 = ldN(BUF0, l), gx1 = ldN(BUF0, 64 + l);
          const short8_t gy0 = ldN(BUF1, l), gy1 = ldN(BUF1, 64 + l);
          layerK64R2<2>(cX, cY, gx0, gx1, gy0, gy1, sW + OFF_W73, l);
        }

        if (it == 0) {
          scatterN_relu(BUF0, cX, q, n);   // new e (cross-lane -> LDS)
          scatterN_relu(BUF1, cY, q, n);
        } else {
          epilogue(cX, sConst, p.out, g0X, q, n, true);
          epilogue(cY, sConst, p.out, g0Y, q, n, okY);
        }
      }
    }
  }
}

extern "C" void kernel_launch(void* const* d_in, const int* in_sizes, int n_in,
                              void* d_out, int out_size, void* d_ws, size_t ws_size,
                              hipStream_t stream) {
  Params p;
  p.ap    = (const float*)d_in[0];
  p.ef    = (const float*)d_in[1];
  p.wpa   = (const float*)d_in[2];  p.bpa   = (const float*)d_in[3];
  p.wpe   = (const float*)d_in[4];  p.bpe   = (const float*)d_in[5];
  p.w51   = (const float*)d_in[6];  p.b51   = (const float*)d_in[7];
  p.w52   = (const float*)d_in[8];  p.b52   = (const float*)d_in[9];
  p.w53   = (const float*)d_in[10]; p.b53   = (const float*)d_in[11];
  p.w61   = (const float*)d_in[12]; p.b61   = (const float*)d_in[13];
  p.w62   = (const float*)d_in[14]; p.b62   = (const float*)d_in[15];
  p.w63   = (const float*)d_in[16]; p.b63   = (const float*)d_in[17];
  p.w71   = (const float*)d_in[18]; p.b71   = (const float*)d_in[19];
  p.w72   = (const float*)d_in[20]; p.b72   = (const float*)d_in[21];
  p.w73   = (const float*)d_in[22]; p.b73   = (const float*)d_in[23];
  p.wpost = (const float*)d_in[24]; p.bpost = (const float*)d_in[25];
  p.out   = (float*)d_out;
  p.gtot  = in_sizes[0] / 4;  // G from ap_feat [G,B,1]

  hipLaunchKernelGGL(hetgnn_mfma, dim3(NBLK), dim3(512), 0, stream, p);
}

// Round 13
// 149.983 us; speedup vs baseline: 2.8743x; 1.0483x over previous
//
#include <hip/hip_runtime.h>

// HetGNN fused kernel, round 27: R25 base (pk2 pack -- v_cvt_pk_bf16_f32 is
// EMPIRICALLY FALSIFIED here: R24/R26 both failed with it, R25 passes without)
// + the last old-layout LDS path (eP / aPb) unified into the pi0 machinery.
// R25's remaining waste: 1.51M bank conflicts, all from the old skewed-u16
// eP/aPb tiles (16 ds_write_b16 + shift-extracts per scatter_bf16; build_h
// uint4 reads). Changes:
//  - eP: raw scatterN (8 ds_write_b32) into BUF; build_h reads the NEIGHBOR
//    lane's fragment rows tp*64 + 16q + re (reader lane = 16q+re, same q, so
//    pi0's q-dependent slot feats match the consumer).
//  - aP: k-dedup new-layout tile: write even graph rows at row' = tp*32 +
//    g*8 + 2q + rh with b61 folded per-feat (feats 32tp+n, 32tp+16+n);
//    read at tp*32 + 8q + (n>>1).
//  - w62 staged with the standard pi0 kidx (h is now pi0-ordered).
// Liveness unchanged: all hf fragments built before the j-loop's first BUF
// overwrite; Eb/T1 alias semantics as in R25. LDS: BUF 1088 + aPb 544 per
// chain -> PW 3264 u16; total 96 + 51 + 4.25 = 151.25 KB, 1 block/CU.
// Base: dual-chain, 512 thr, (2,2), ~116 VGPR no-spill, LDSFENCE discipline.

typedef unsigned short u16;
typedef unsigned int   u32;
typedef __attribute__((ext_vector_type(8))) short short8_t;
typedef __attribute__((ext_vector_type(2))) short short2v;
typedef __attribute__((ext_vector_type(4))) float floatx4;

#define LDSFENCE() asm volatile("" ::: "memory")

// u16 offsets of each matrix's fragment block inside sW (fi*512 ordering).
// 96 frags: w51(16) w61(16) w71(16) w52(8) w53(8) w62(8) w63(8) w72(8) w73(8).
#define OFF_W51 0
#define OFF_W61 8192
#define OFF_W71 16384
#define OFF_W52 24576
#define OFF_W53 28672
#define OFF_W62 32768
#define OFF_W63 36864
#define OFF_W72 40960
#define OFF_W73 45056
#define WS_U16  49152

// f32 offsets inside the sConst LDS table.
#define CB51 0
#define CB52 64
#define CB53 128
#define CB61 192
#define CB62 256
#define CB63 320
#define CB71 384
#define CB72 448
#define CB73 512
#define CWPO 576
#define CBPO 704
#define CWPA 768
#define CBPA 832
#define CWPE 896
#define CBPE 1024
#define CSZ  1088

// new-layout tiles: BUF 128 rows -> 1080 u16 (pad 1088); aPb 64 rows -> 536 (pad 544)
#define BUF_U16 1088
#define APB_U16 544
#define PW_U16  3264   // 2 chains x (BUF | aPb)

struct Params {
  const float *ap, *ef;
  const float *wpa, *bpa, *wpe, *bpe;
  const float *w51, *b51, *w52, *b52, *w53, *b53;
  const float *w61, *b61, *w62, *b62, *w63, *b63;
  const float *w71, *b71, *w72, *b72, *w73, *b73;
  const float *wpost, *bpost;
  float *out;
  int gtot;
};

// Pack two f32 to bf16 pair: round-half-up via +0x8000, then one byte-perm.
// Low half = first arg. (PROVEN form; v_cvt_pk_bf16_f32 asm fails here.)
__device__ __forceinline__ u32 pk2(float a, float b) {
  const u32 ua = __float_as_uint(a) + 0x8000u;
  const u32 ub = __float_as_uint(b) + 0x8000u;
  return __builtin_amdgcn_perm(ub, ua, 0x07060302u);  // {ub[31:16], ua[31:16]}
}
__device__ __forceinline__ float blo(u32 v) { return __uint_as_float(v << 16); }
__device__ __forceinline__ float bhi(u32 v) { return __uint_as_float(v & 0xffff0000u); }
// packed int16 max: exact bf16-max in our use because the final max-with-0
// (deferred relu) dominates any mis-ordered negative intermediate.
__device__ __forceinline__ u32 pkmax(u32 a, u32 b) {
  const short2v r = __builtin_elementwise_max(__builtin_bit_cast(short2v, a),
                                              __builtin_bit_cast(short2v, b));
  return __builtin_bit_cast(u32, r);
}
__device__ __forceinline__ float sel4(int i, float x0, float x1, float x2, float x3) {
  const float lo = (i & 1) ? x1 : x0;
  const float hi = (i & 1) ? x3 : x2;
  return (i & 2) ? hi : lo;
}

__device__ __forceinline__ floatx4 mfma16(short8_t a, short8_t b, floatx4 c) {
  return __builtin_amdgcn_mfma_f32_16x16x32_bf16(a, b, c, 0, 0, 0);
}
// new-layout row start (u16 index): row*16B + 16B skew per 16 rows
__device__ __forceinline__ int rowN(int row) { return row * 8 + (row >> 4) * 8; }
// new-layout gather: loads through uint4 (int family) so it orders against
// the u32 scatters under TBAA.
__device__ __forceinline__ short8_t ldN(const u16* buf, int row) {
  const uint4 v = *(const uint4*)(buf + rowN(row));
  return __builtin_bit_cast(short8_t, v);
}
__device__ __forceinline__ uint4 ldN4(const u16* buf, int row) {
  return *(const uint4*)(buf + rowN(row));
}

// Dual-chain K=64 layer: each B fragment is loaded ONCE and feeds both chains.
template<int TSTRIDE>
__device__ __forceinline__ void layerK64R2(floatx4* aX, floatx4* aY,
                                           short8_t x0, short8_t x1,
                                           short8_t y0, short8_t y1,
                                           const u16* B, int l) {
#pragma unroll
  for (int t = 0; t < 4; ++t) {
    const short8_t b0 = *(const short8_t*)(B + (t * TSTRIDE + 0) * 512 + l * 8);
    const short8_t b1 = *(const short8_t*)(B + (t * TSTRIDE + 1) * 512 + l * 8);
    aX[t] = mfma16(x0, b0, aX[t]);
    aY[t] = mfma16(y0, b0, aY[t]);
    aX[t] = mfma16(x1, b1, aX[t]);
    aY[t] = mfma16(y1, b1, aY[t]);
  }
}

// Dual-chain K=128 layer (4 A-frags per chain), shared B loads.
__device__ __forceinline__ void layerK128R2(floatx4* aX, floatx4* aY,
                                            const short8_t* fx, const short8_t* fy,
                                            const u16* B, int l) {
#pragma unroll
  for (int t = 0; t < 4; ++t)
#pragma unroll
    for (int h = 0; h < 4; ++h) {
      const short8_t b = *(const short8_t*)(B + (t * 4 + h) * 512 + l * 8);
      aX[t] = mfma16(fx[h], b, aX[t]);
      aY[t] = mfma16(fy[h], b, aY[t]);
    }
}

// pi0 scatter: u32 (tp, r) from lane (q,n) -> row tp*64 + g*16 + 4q + r,
// dword n&3. relu via packed pkmax0. 8 ds_write_b32, 2 lanes/bank.
__device__ __forceinline__ void scatterN_relu(u16* dst, const floatx4* acc, int q, int n) {
  u32* d32 = (u32*)dst;
  const int g = n >> 2, d = n & 3;
#pragma unroll
  for (int tp = 0; tp < 2; ++tp)
#pragma unroll
    for (int r = 0; r < 4; ++r) {
      const int row = tp * 64 + g * 16 + 4 * q + r;
      d32[row * 4 + (row >> 4) * 4 + d] =
          pkmax(pk2(acc[2 * tp + 0][r], acc[2 * tp + 1][r]), 0u);
    }
  LDSFENCE();
}
// same, raw pack (eP can be negative; relu deferred).
__device__ __forceinline__ void scatterN_raw(u16* dst, const floatx4* acc, int q, int n) {
  u32* d32 = (u32*)dst;
  const int g = n >> 2, d = n & 3;
#pragma unroll
  for (int tp = 0; tp < 2; ++tp)
#pragma unroll
    for (int r = 0; r < 4; ++r) {
      const int row = tp * 64 + g * 16 + 4 * q + r;
      d32[row * 4 + (row >> 4) * 4 + d] = pk2(acc[2 * tp + 0][r], acc[2 * tp + 1][r]);
    }
  LDSFENCE();
}
// scatter of pre-packed u32s (v[tp*4+r]).
__device__ __forceinline__ void scatterN_u32(u16* dst, const u32* v, int q, int n) {
  u32* d32 = (u32*)dst;
  const int g = n >> 2, d = n & 3;
#pragma unroll
  for (int tp = 0; tp < 2; ++tp)
#pragma unroll
    for (int r = 0; r < 4; ++r) {
      const int row = tp * 64 + g * 16 + 4 * q + r;
      d32[row * 4 + (row >> 4) * 4 + d] = v[tp * 4 + r];
    }
  LDSFENCE();
}

// aP: k-dedup new-layout scatter (even graph rows only; rows 4q+rr and
// 4q+rr+1 are k-duplicates), b61 folded per-feat. Dedup row' = full_row>>1.
__device__ __forceinline__ void scatter_aP(u16* dst, const floatx4* acc, int q, int n,
                                           const float* cb61) {
  u32* d32 = (u32*)dst;
  const int g = n >> 2, d = n & 3;
#pragma unroll
  for (int tp = 0; tp < 2; ++tp) {
    const float bv0 = cb61[32 * tp + n];        // feat of acc[2tp]   = 32tp+n
    const float bv1 = cb61[32 * tp + 16 + n];   // feat of acc[2tp+1] = 32tp+16+n
#pragma unroll
    for (int rh = 0; rh < 2; ++rh) {            // rr = 2*rh (even rows)
      const int row = tp * 32 + g * 8 + 2 * q + rh;
      d32[row * 4 + (row >> 4) * 4 + d] =
          pk2(acc[2 * tp + 0][2 * rh] + bv0, acc[2 * tp + 1][2 * rh] + bv1);
    }
  }
  LDSFENCE();
}

__device__ __forceinline__ void init_accL(floatx4* acc, const float* cb, int n) {
#pragma unroll
  for (int t = 0; t < 4; ++t) {
    const float b = cb[16 * t + n];
    floatx4 v; v[0] = b; v[1] = b; v[2] = b; v[3] = b;
    acc[t] = v;
  }
}
__device__ __forceinline__ void init_acc0(floatx4* acc) {
#pragma unroll
  for (int t = 0; t < 4; ++t) { acc[t][0] = 0.f; acc[t][1] = 0.f; acc[t][2] = 0.f; acc[t][3] = 0.f; }
}

struct frag2 { short8_t f0, f1; };

__device__ __forceinline__ frag2 make_a(float apv, int q, const float* sc) {
  frag2 r;
#pragma unroll
  for (int h = 0; h < 2; ++h) {
    const int fb = 32 * h + 8 * q;
    const float4 wa0 = *(const float4*)(sc + CWPA + fb);
    const float4 wa1 = *(const float4*)(sc + CWPA + fb + 4);
    const float4 ba0 = *(const float4*)(sc + CBPA + fb);
    const float4 ba1 = *(const float4*)(sc + CBPA + fb + 4);
    uint4 pa;
    pa.x = pk2(fmaxf(fmaf(apv, wa0.x, ba0.x), 0.f), fmaxf(fmaf(apv, wa0.y, ba0.y), 0.f));
    pa.y = pk2(fmaxf(fmaf(apv, wa0.z, ba0.z), 0.f), fmaxf(fmaf(apv, wa0.w, ba0.w), 0.f));
    pa.z = pk2(fmaxf(fmaf(apv, wa1.x, ba1.x), 0.f), fmaxf(fmaf(apv, wa1.y, ba1.y), 0.f));
    pa.w = pk2(fmaxf(fmaf(apv, wa1.z, ba1.z), 0.f), fmaxf(fmaf(apv, wa1.w, ba1.w), 0.f));
    if (h == 0) r.f0 = __builtin_bit_cast(short8_t, pa);
    else        r.f1 = __builtin_bit_cast(short8_t, pa);
  }
  return r;
}

// Pre-layer for one chain (tables are pi0-permuted at staging).
__device__ __forceinline__ void prelayer(frag2& A, short8_t& e0, short8_t& e1,
                                         const Params& p, const float* sc,
                                         int g0, int q, int n) {
  const float apv = p.ap[(g0 + (n >> 3)) * 4 + ((n >> 1) & 3)];
  A = make_a(apv, q, sc);
  const float f0 = p.ef[(g0 + (n >> 3)) * 16 + (n & 7) * 2];
  const float f1 = p.ef[(g0 + (n >> 3)) * 16 + (n & 7) * 2 + 1];
#pragma unroll
  for (int h = 0; h < 2; ++h) {
    const int fb = 32 * h + 8 * q;
    const float4 w00 = *(const float4*)(sc + CWPE + fb);
    const float4 w01 = *(const float4*)(sc + CWPE + fb + 4);
    const float4 w10 = *(const float4*)(sc + CWPE + 64 + fb);
    const float4 w11 = *(const float4*)(sc + CWPE + 64 + fb + 4);
    const float4 be0 = *(const float4*)(sc + CBPE + fb);
    const float4 be1 = *(const float4*)(sc + CBPE + fb + 4);
    uint4 pe;
    pe.x = pk2(fmaxf(fmaf(f0, w00.x, fmaf(f1, w10.x, be0.x)), 0.f),
               fmaxf(fmaf(f0, w00.y, fmaf(f1, w10.y, be0.y)), 0.f));
    pe.y = pk2(fmaxf(fmaf(f0, w00.z, fmaf(f1, w10.z, be0.z)), 0.f),
               fmaxf(fmaf(f0, w00.w, fmaf(f1, w10.w, be0.w)), 0.f));
    pe.z = pk2(fmaxf(fmaf(f0, w01.x, fmaf(f1, w11.x, be1.x)), 0.f),
               fmaxf(fmaf(f0, w01.y, fmaf(f1, w11.y, be1.y)), 0.f));
    pe.w = pk2(fmaxf(fmaf(f0, w01.z, fmaf(f1, w11.z, be1.z)), 0.f),
               fmaxf(fmaf(f0, w01.w, fmaf(f1, w11.w, be1.w)), 0.f));
    if (h == 0) e0 = __builtin_bit_cast(short8_t, pe);
    else        e1 = __builtin_bit_cast(short8_t, pe);
  }
}

// Build the 3 neighbor-tile h fragments for one chain, all-pi0 layout:
// own aP (dedup rows) + neighbor eP (fragment rows of lane 16q+re).
__device__ __forceinline__ void build_h(short8_t* hf0, short8_t* hf1,
                                        const u16* aPb, const u16* BUF,
                                        int q, int n) {
  const int b_ln = (n >> 1) & 3;
  const int ar = 8 * q + (n >> 1);
  const uint4 av0 = ldN4(aPb, ar);
  const uint4 av1 = ldN4(aPb, 32 + ar);
#pragma unroll
  for (int j = 0; j < 3; ++j) {
    const int bp = j + (j >= b_ln);   // j-th neighbor of b_ln
    const int re = (n & 8) + bp * 2 + (n & 1);
    const uint4 ev0 = ldN4(BUF, 16 * q + re);
    const uint4 ev1 = ldN4(BUF, 64 + 16 * q + re);
    uint4 p0, p1;
    p0.x = pk2(fmaxf(blo(av0.x) + blo(ev0.x), 0.f), fmaxf(bhi(av0.x) + bhi(ev0.x), 0.f));
    p0.y = pk2(fmaxf(blo(av0.y) + blo(ev0.y), 0.f), fmaxf(bhi(av0.y) + bhi(ev0.y), 0.f));
    p0.z = pk2(fmaxf(blo(av0.z) + blo(ev0.z), 0.f), fmaxf(bhi(av0.z) + bhi(ev0.z), 0.f));
    p0.w = pk2(fmaxf(blo(av0.w) + blo(ev0.w), 0.f), fmaxf(bhi(av0.w) + bhi(ev0.w), 0.f));
    p1.x = pk2(fmaxf(blo(av1.x) + blo(ev1.x), 0.f), fmaxf(bhi(av1.x) + bhi(ev1.x), 0.f));
    p1.y = pk2(fmaxf(blo(av1.y) + blo(ev1.y), 0.f), fmaxf(bhi(av1.y) + bhi(ev1.y), 0.f));
    p1.z = pk2(fmaxf(blo(av1.z) + blo(ev1.z), 0.f), fmaxf(bhi(av1.z) + bhi(ev1.z), 0.f));
    p1.w = pk2(fmaxf(blo(av1.w) + blo(ev1.w), 0.f), fmaxf(bhi(av1.w) + bhi(ev1.w), 0.f));
    hf0[j] = __builtin_bit_cast(short8_t, p0);
    hf1[j] = __builtin_bit_cast(short8_t, p1);
  }
}

// Post linear + per-(g,b) L2 row normalization for one chain.
__device__ __forceinline__ void epilogue(const floatx4* acc3, const float* sc,
                                         float* out, int g0, int q, int n, bool ok) {
  float prr[4] = {0.f, 0.f, 0.f, 0.f}, pii[4] = {0.f, 0.f, 0.f, 0.f};
#pragma unroll
  for (int t = 0; t < 4; ++t) {
    const float wr = sc[CWPO + (16 * t + n) * 2];
    const float wi = sc[CWPO + (16 * t + n) * 2 + 1];
#pragma unroll
    for (int r = 0; r < 4; ++r) {
      const float e = fmaxf(acc3[t][r], 0.f);
      prr[r] = fmaf(e, wr, prr[r]);
      pii[r] = fmaf(e, wi, pii[r]);
    }
  }
  const float bpR = sc[CBPO], bpI = sc[CBPO + 1];
#pragma unroll
  for (int r = 0; r < 4; ++r) {
#pragma unroll
    for (int off = 1; off < 16; off <<= 1) {
      prr[r] += __shfl_xor(prr[r], off, 16);
      pii[r] += __shfl_xor(pii[r], off, 16);
    }
    prr[r] += bpR;
    pii[r] += bpI;
  }
  const int r = n >> 1, c = n & 1, rp = r ^ 1;
  const float pr_r  = sel4(r,  prr[0], prr[1], prr[2], prr[3]);
  const float pi_r  = sel4(r,  pii[0], pii[1], pii[2], pii[3]);
  const float pr_rp = sel4(rp, prr[0], prr[1], prr[2], prr[3]);
  const float pi_rp = sel4(rp, pii[0], pii[1], pii[2], pii[3]);
  const float num = c ? pi_r : pr_r;
  const float n2  = pr_r * pr_r + pi_r * pi_r + pr_rp * pr_rp + pi_rp * pi_rp;
  if (ok && n < 8) out[g0 * 16 + (4 * q + r) * 2 + c] = num / sqrtf(n2);
}

#define NBLK 256
#define NWAVE 8
#define PPW  2   // 256 blk * 8 waves * 2 chains * 2 = 8192 pairs = 16384 graphs

__global__ __launch_bounds__(512, 2)
__attribute__((amdgpu_waves_per_eu(2, 2)))
void hetgnn_mfma(Params p) {
  __shared__ __align__(16) u16   sW[WS_U16];            // 96 KB weights
  __shared__ __align__(16) u16   sAct[NWAVE * PW_U16];  // 51 KB: 8 x 2 x (BUF|aPb)
  __shared__ __align__(16) float sConst[CSZ];           // 4.25 KB

  const int tid  = threadIdx.x;
  const int wave = tid >> 6;
  const int l    = tid & 63;
  const int q    = l >> 4;
  const int n    = l & 15;

  // ---- stage + swizzle weights (f32 global -> bf16 B-frag LDS), 96 frags.
  //      pi0 k-order for ALL mats (w62 included: h is now pi0-ordered).
  {
    for (int fi = wave; fi < 96; fi += NWAVE) {   // wave-uniform fi, 12/wave
      int t, h, mi;
      if (fi < 48) { mi = fi >> 4; const int loc = fi & 15; t = loc >> 2; h = loc & 3; }
      else { const int j = fi - 48; mi = 3 + (j >> 3); const int loc = j & 7; t = loc >> 1; h = loc & 1; }
      const float* W =
          (mi == 0) ? p.w51 : (mi == 1) ? p.w61 : (mi == 2) ? p.w71 :
          (mi == 3) ? p.w52 : (mi == 4) ? p.w53 : (mi == 5) ? p.w62 :
          (mi == 6) ? p.w63 : (mi == 7) ? p.w72 : p.w73;
      const int nn = 16 * t + n;
      float w[8];
#pragma unroll
      for (int jj = 0; jj < 8; ++jj) {
        const int kidx = (fi < 48)
            ? 64 * (h >> 1) + 32 * (h & 1) + (jj & 1) * 16 + 4 * q + (jj >> 1)
            : 32 * h + (jj & 1) * 16 + 4 * q + (jj >> 1);
        w[jj] = W[kidx * 64 + nn];
      }
      uint4 o;
      o.x = pk2(w[0], w[1]); o.y = pk2(w[2], w[3]);
      o.z = pk2(w[4], w[5]); o.w = pk2(w[6], w[7]);
      *(uint4*)(sW + fi * 512 + l * 8) = o;
    }
  }
  if (tid < 64) {
    sConst[CB51 + tid] = p.b51[tid];
    sConst[CB52 + tid] = p.b52[tid];
    sConst[CB53 + tid] = p.b53[tid];
    sConst[CB61 + tid] = p.b61[tid];
    sConst[CB62 + tid] = p.b62[tid];
    sConst[CB63 + tid] = p.b63[tid];
    sConst[CB71 + tid] = p.b71[tid];
    sConst[CB72 + tid] = p.b72[tid];
    sConst[CB73 + tid] = p.b73[tid];
    // pre-layer tables permuted to pi0 slot order:
    // slot s holds feat = 32*(s>>5) + (s&1)*16 + 4*((s>>3)&3) + ((s>>1)&3)
    const int feat = 32 * (tid >> 5) + (tid & 1) * 16 + 4 * ((tid >> 3) & 3) + ((tid >> 1) & 3);
    sConst[CWPA + tid] = p.wpa[feat];
    sConst[CBPA + tid] = p.bpa[feat];
    sConst[CBPE + tid] = p.bpe[feat];
  }
  if (tid < 128) {
    sConst[CWPO + tid] = p.wpost[tid];
    const int s = tid & 63;
    const int feat = 32 * (s >> 5) + (s & 1) * 16 + 4 * ((s >> 3) & 3) + ((s >> 1) & 3);
    sConst[CWPE + tid] = p.wpe[(tid >> 6) * 64 + feat];
  }
  if (tid < 2) sConst[CBPO + tid] = p.bpost[tid];
  __syncthreads();

  u16* BUF0 = sAct + wave * PW_U16;   // chain X: T1 = eP = Eb alias (pi0 tile)
  u16* aPb0 = BUF0 + BUF_U16;
  u16* BUF1 = aPb0 + APB_U16;         // chain Y
  u16* aPb1 = BUF1 + BUF_U16;

  const int wslot = blockIdx.x * NWAVE + wave;

#pragma unroll 1
  for (int pi = 0; pi < PPW; ++pi) {
    const int g0X = (wslot * 4 + 2 * pi) * 2;   // chain X: graphs g0X, g0X+1
    const int g0Y = g0X + 2;                    // chain Y: graphs g0Y, g0Y+1
    if (g0X + 2 > p.gtot) break;
    const bool okY = (g0Y + 2 <= p.gtot);
    const int gY  = okY ? g0Y : g0X;            // safe index for loads

    // ---------------- pre-layer, both chains ----------------
    frag2 AX, AY;
    short8_t ex0, ex1, ey0, ey1;
    prelayer(AX, ex0, ex1, p, sConst, g0X, q, n);
    prelayer(AY, ey0, ey1, p, sConst, gY,  q, n);

    // ---- aP = a @ w61[:64] (+ b61 pre-fold), dedup pi0 tile (it-invariant) ----
    {
      floatx4 aaX[4], aaY[4];
      init_acc0(aaX); init_acc0(aaY);
      layerK64R2<4>(aaX, aaY, AX.f0, AX.f1, AY.f0, AY.f1, sW + OFF_W61, l);
      scatter_aP(aPb0, aaX, q, n, sConst + CB61);
      scatter_aP(aPb1, aaY, q, n, sConst + CB61);
    }

    // ---------------- 2 shared-weight update iterations ----------------
#pragma unroll 1
    for (int it = 0; it < 2; ++it) {
      if (it == 1) {
        ex0 = ldN(BUF0, l); ex1 = ldN(BUF0, 64 + l);   // new e from it0
        ey0 = ldN(BUF1, l); ey1 = ldN(BUF1, 64 + l);
      }

      // ---- mlp5 -> m1 (tpair-packed raw bf16; relu deferred to agg) ----
      u32 m1pX[8], m1pY[8];
      {
        floatx4 aX[4], aY[4];
        init_accL(aX, sConst + CB51, n); init_accL(aY, sConst + CB51, n);
        const short8_t fx[4] = {AX.f0, AX.f1, ex0, ex1};
        const short8_t fy[4] = {AY.f0, AY.f1, ey0, ey1};
        layerK128R2(aX, aY, fx, fy, sW + OFF_W51, l);
        scatterN_relu(BUF0, aX, q, n);
        scatterN_relu(BUF1, aY, q, n);
        floatx4 bX[4], bY[4];
        init_accL(bX, sConst + CB52, n); init_accL(bY, sConst + CB52, n);
        {
          const short8_t gx0 = ldN(BUF0, l), gx1 = ldN(BUF0, 64 + l);
          const short8_t gy0 = ldN(BUF1, l), gy1 = ldN(BUF1, 64 + l);
          layerK64R2<2>(bX, bY, gx0, gx1, gy0, gy1, sW + OFF_W52, l);
        }
        scatterN_relu(BUF0, bX, q, n);
        scatterN_relu(BUF1, bY, q, n);
        floatx4 cX[4], cY[4];
        init_accL(cX, sConst + CB53, n); init_accL(cY, sConst + CB53, n);
        {
          const short8_t gx0 = ldN(BUF0, l), gx1 = ldN(BUF0, 64 + l);
          const short8_t gy0 = ldN(BUF1, l), gy1 = ldN(BUF1, 64 + l);
          layerK64R2<2>(cX, cY, gx0, gx1, gy0, gy1, sW + OFF_W53, l);
        }
#pragma unroll
        for (int tp = 0; tp < 2; ++tp)
#pragma unroll
          for (int r = 0; r < 4; ++r) {
            m1pX[tp * 4 + r] = pk2(cX[2 * tp][r], cX[2 * tp + 1][r]);
            m1pY[tp * 4 + r] = pk2(cY[2 * tp][r], cY[2 * tp + 1][r]);
          }
      }

      // ---- mlp6 -> m2: 3 neighbor-tiles; hf hoisted so eP (=BUF) dies
      //      before the first T1 (=BUF) scatter of the j-loop ----
      u32 m2pX[8], m2pY[8];
      {
        floatx4 eX[4], eY[4];
        init_acc0(eX); init_acc0(eY);
        layerK64R2<4>(eX, eY, ex0, ex1, ey0, ey1, sW + OFF_W61 + 2 * 512, l);
        scatterN_raw(BUF0, eX, q, n);   // eP, pi0 tile
        scatterN_raw(BUF1, eY, q, n);

        short8_t hfX0[3], hfX1[3], hfY0[3], hfY1[3];
        build_h(hfX0, hfX1, aPb0, BUF0, q, n);
        build_h(hfY0, hfY1, aPb1, BUF1, q, n);

#pragma unroll
        for (int j = 0; j < 3; ++j) {
          floatx4 uX[4], uY[4];
          init_accL(uX, sConst + CB62, n); init_accL(uY, sConst + CB62, n);
          layerK64R2<2>(uX, uY, hfX0[j], hfX1[j], hfY0[j], hfY1[j], sW + OFF_W62, l);
          scatterN_relu(BUF0, uX, q, n);
          scatterN_relu(BUF1, uY, q, n);
          floatx4 vX[4], vY[4];
          init_accL(vX, sConst + CB63, n); init_accL(vY, sConst + CB63, n);
          {
            const short8_t gx0 = ldN(BUF0, l), gx1 = ldN(BUF0, 64 + l);
            const short8_t gy0 = ldN(BUF1, l), gy1 = ldN(BUF1, 64 + l);
            layerK64R2<2>(vX, vY, gx0, gx1, gy0, gy1, sW + OFF_W63, l);
          }
#pragma unroll
          for (int tp = 0; tp < 2; ++tp)
#pragma unroll
            for (int r = 0; r < 4; ++r) {
              const u32 cXv = pk2(vX[2 * tp][r], vX[2 * tp + 1][r]);
              const u32 cYv = pk2(vY[2 * tp][r], vY[2 * tp + 1][r]);
              const int i = tp * 4 + r;
              m2pX[i] = (j == 0) ? cXv : pkmax(m2pX[i], cXv);
              m2pY[i] = (j == 0) ? cYv : pkmax(m2pY[i], cYv);
            }
        }
      }

      // ---- agg = relu(max(m1[k^1], m2)): k-swap is a register index swap ----
      {
        u32 agX[8], agY[8];
#pragma unroll
        for (int tp = 0; tp < 2; ++tp)
#pragma unroll
          for (int r = 0; r < 4; ++r) {
            const int i = tp * 4 + r;
            agX[i] = pkmax(pkmax(m1pX[tp * 4 + (r ^ 1)], m2pX[i]), 0u);
            agY[i] = pkmax(pkmax(m1pY[tp * 4 + (r ^ 1)], m2pY[i]), 0u);
          }
        scatterN_u32(BUF0, agX, q, n);
        scatterN_u32(BUF1, agY, q, n);
        floatx4 aX[4], aY[4];
        init_accL(aX, sConst + CB71, n); init_accL(aY, sConst + CB71, n);
        {
          const short8_t gx0 = ldN(BUF0, l), gx1 = ldN(BUF0, 64 + l);
          const short8_t gy0 = ldN(BUF1, l), gy1 = ldN(BUF1, 64 + l);
          const short8_t fx[4] = {gx0, gx1, ex0, ex1};
          const short8_t fy[4] = {gy0, gy1, ey0, ey1};
          layerK128R2(aX, aY, fx, fy, sW + OFF_W71, l);
        }
        scatterN_relu(BUF0, aX, q, n);
        scatterN_relu(BUF1, aY, q, n);
        floatx4 bX[4], bY[4];
        init_accL(bX, sConst + CB72, n); init_accL(bY, sConst + CB72, n);
        {
          const short8_t gx0 = ldN(BUF0, l), gx1 = ldN(BUF0, 64 + l);
          const short8_t gy0 = ldN(BUF1, l), gy1 = ldN(BUF1, 64 + l);
          layerK64R2<2>(bX, bY, gx0, gx1, gy0, gy1, sW + OFF_W72, l);
        }
        scatterN_relu(BUF0, bX, q, n);
        scatterN_relu(BUF1, bY, q, n);
        floatx4 cX[4], cY[4];
        init_accL(cX, sConst + CB73, n); init_accL(cY, sConst + CB73, n);
        {
          const short8_t gx0 = ldN(BUF0, l), gx1 = ldN(BUF0, 64 + l);
          const short8_t gy0 = ldN(BUF1, l), gy1 = ldN(BUF1, 64 + l);
          layerK64R2<2>(cX, cY, gx0, gx1, gy0, gy1, sW + OFF_W73, l);
        }

        if (it == 0) {
          scatterN_relu(BUF0, cX, q, n);   // new e (cross-lane -> LDS)
          scatterN_relu(BUF1, cY, q, n);
        } else {
          epilogue(cX, sConst, p.out, g0X, q, n, true);
          epilogue(cY, sConst, p.out, g0Y, q, n, okY);
        }
      }
    }
  }
}

extern "C" void kernel_launch(void* const* d_in, const int* in_sizes, int n_in,
                              void* d_out, int out_size, void* d_ws, size_t ws_size,
                              hipStream_t stream) {
  Params p;
  p.ap    = (const float*)d_in[0];
  p.ef    = (const float*)d_in[1];
  p.wpa   = (const float*)d_in[2];  p.bpa   = (const float*)d_in[3];
  p.wpe   = (const float*)d_in[4];  p.bpe   = (const float*)d_in[5];
  p.w51   = (const float*)d_in[6];  p.b51   = (const float*)d_in[7];
  p.w52   = (const float*)d_in[8];  p.b52   = (const float*)d_in[9];
  p.w53   = (const float*)d_in[10]; p.b53   = (const float*)d_in[11];
  p.w61   = (const float*)d_in[12]; p.b61   = (const float*)d_in[13];
  p.w62   = (const float*)d_in[14]; p.b62   = (const float*)d_in[15];
  p.w63   = (const float*)d_in[16]; p.b63   = (const float*)d_in[17];
  p.w71   = (const float*)d_in[18]; p.b71   = (const float*)d_in[19];
  p.w72   = (const float*)d_in[20]; p.b72   = (const float*)d_in[21];
  p.w73   = (const float*)d_in[22]; p.b73   = (const float*)d_in[23];
  p.wpost = (const float*)d_in[24]; p.bpost = (const float*)d_in[25];
  p.out   = (float*)d_out;
  p.gtot  = in_sizes[0] / 4;  // G from ap_feat [G,B,1]

  hipLaunchKernelGGL(hetgnn_mfma, dim3(NBLK), dim3(512), 0, stream, p);
}